// Round 3
// 216.635 us; speedup vs baseline: 1.3084x; 1.3084x over previous
//
#include <hip/hip_runtime.h>
#include <math.h>

#define L_SEQ 4096
#define C_DIM 512
#define NH 8
#define DK 64
#define NB 2
#define QSC 0.18033688011112042f  /* (1/sqrt(64)) * log2(e) */

typedef _Float16 f16;
typedef _Float16 f16x8 __attribute__((ext_vector_type(8)));
typedef _Float16 f16x4 __attribute__((ext_vector_type(4)));
typedef __fp16 h16x2 __attribute__((ext_vector_type(2)));   // builtin ABI type
typedef float f32x4 __attribute__((ext_vector_type(4)));
typedef float f32x16 __attribute__((ext_vector_type(16)));
typedef unsigned int u32;

// ---------------------------------------------------------------------------
// prep: z=0,1 -> transpose-cast X[b] [512][4096] fp32 -> Xt [b*4096+t][512] f16
//       z=2   -> plain-cast Wq, Wkv[0:512], Wkv[512:1024], Wp -> f16
// ---------------------------------------------------------------------------
__global__ __launch_bounds__(256) void prep(
    const float* __restrict__ X, const float* __restrict__ Wq,
    const float* __restrict__ Wkv, const float* __restrict__ Wp,
    f16* __restrict__ Xt, f16* __restrict__ Wqkh,
    f16* __restrict__ Wvh, f16* __restrict__ Wph)
{
    const int tid = threadIdx.x;
    const int z = blockIdx.z;
    if (z < 2) {
        __shared__ f16 Ts[64][72];
        const float* src = X + (size_t)z * C_DIM * L_SEQ;
        f16* dst = Xt + (size_t)z * L_SEQ * C_DIM;
        for (int tile = blockIdx.x; tile < 512; tile += gridDim.x) {
            const int c0 = (tile & 7) * 64;
            const int t0 = (tile >> 3) * 64;
            __syncthreads();
            #pragma unroll
            for (int p = 0; p < 4; ++p) {
                const int c = (tid >> 4) + p * 16;
                const int t = (tid & 15) * 4;
                const float4 v = *(const float4*)(src + (size_t)(c0 + c) * L_SEQ + t0 + t);
                Ts[t + 0][c] = (f16)v.x; Ts[t + 1][c] = (f16)v.y;
                Ts[t + 2][c] = (f16)v.z; Ts[t + 3][c] = (f16)v.w;
            }
            __syncthreads();
            #pragma unroll
            for (int p = 0; p < 2; ++p) {
                const int t = (tid >> 3) + p * 32;
                const int ch = (tid & 7) * 8;
                *(f16x8*)(dst + (size_t)(t0 + t) * C_DIM + c0 + ch) =
                    *(const f16x8*)&Ts[t][ch];
            }
        }
    } else {
        const float* srcs[4] = {Wq, Wkv, Wkv + 262144, Wp};
        f16* dsts[4] = {Wqkh, Wqkh + 262144, Wvh, Wph};
        #pragma unroll
        for (int s = 0; s < 4; ++s) {
            const float* sp = srcs[s]; f16* dp = dsts[s];
            for (int i = blockIdx.x * 256 + tid; i < 65536; i += gridDim.x * 256) {
                const float4 v = *(const float4*)(sp + (size_t)i * 4);
                f16x4 h; h[0] = (f16)v.x; h[1] = (f16)v.y; h[2] = (f16)v.z; h[3] = (f16)v.w;
                *(f16x4*)(dp + (size_t)i * 4) = h;
            }
        }
    }
}

// ---------------------------------------------------------------------------
// Q/K projection, fp16 MFMA. m = tokens (global 8192), n = channels (1024).
// A = Xt[t][c], B = Wqkh[o][c]. C row=t, col=o. Q scaled by QSC.
// Outputs token-major Qh/Kh [bh][t][64].
// ---------------------------------------------------------------------------
__global__ __launch_bounds__(256) void qk_mfma(
    const f16* __restrict__ Xt, const f16* __restrict__ Wqkh,
    const float* __restrict__ bq, const float* __restrict__ bkv,
    f16* __restrict__ Qh, f16* __restrict__ Kh)
{
    __shared__ f16 As[128][40];
    __shared__ f16 Bs[128][40];
    const int tid = threadIdx.x;
    const int lane = tid & 63, w = tid >> 6;
    const int l15 = lane & 15, quad = lane >> 4;
    const int wy = w >> 1, wx = w & 1;
    const int mb0 = blockIdx.x * 128;   // token tile
    const int n0  = blockIdx.y * 128;   // channel tile

    f32x4 acc[4][4] = {};
    const int row = tid >> 2, c8 = (tid & 3) * 8;
    const f16* aptr = Xt + (size_t)mb0 * 512;
    const f16* bptr = Wqkh + (size_t)n0 * 512;

    uint4 ga0 = *(const uint4*)(aptr + (size_t)row * 512 + c8);
    uint4 ga1 = *(const uint4*)(aptr + (size_t)(row + 64) * 512 + c8);
    uint4 gb0 = *(const uint4*)(bptr + (size_t)row * 512 + c8);
    uint4 gb1 = *(const uint4*)(bptr + (size_t)(row + 64) * 512 + c8);

    for (int k0 = 0; k0 < 512; k0 += 32) {
        __syncthreads();
        *(uint4*)&As[row][c8] = ga0;
        *(uint4*)&As[row + 64][c8] = ga1;
        *(uint4*)&Bs[row][c8] = gb0;
        *(uint4*)&Bs[row + 64][c8] = gb1;
        if (k0 + 32 < 512) {
            ga0 = *(const uint4*)(aptr + (size_t)row * 512 + k0 + 32 + c8);
            ga1 = *(const uint4*)(aptr + (size_t)(row + 64) * 512 + k0 + 32 + c8);
            gb0 = *(const uint4*)(bptr + (size_t)row * 512 + k0 + 32 + c8);
            gb1 = *(const uint4*)(bptr + (size_t)(row + 64) * 512 + k0 + 32 + c8);
        }
        __syncthreads();
        f16x8 af[4], bf[4];
        #pragma unroll
        for (int i = 0; i < 4; ++i)
            af[i] = *(const f16x8*)&As[wy * 64 + i * 16 + l15][quad * 8];
        #pragma unroll
        for (int n = 0; n < 4; ++n)
            bf[n] = *(const f16x8*)&Bs[wx * 64 + n * 16 + l15][quad * 8];
        #pragma unroll
        for (int i = 0; i < 4; ++i)
            #pragma unroll
            for (int n = 0; n < 4; ++n)
                acc[i][n] = __builtin_amdgcn_mfma_f32_16x16x32_f16(af[i], bf[n], acc[i][n], 0, 0, 0);
    }

    #pragma unroll
    for (int nn = 0; nn < 4; ++nn) {
        const int o = n0 + wx * 64 + nn * 16 + l15;
        const bool isQ = (o < 512);
        const float bias = isQ ? bq[o] : bkv[o - 512];
        const int h = (o & 511) >> 6, d = o & 63;
        f16* base = isQ ? Qh : Kh;
        #pragma unroll
        for (int i = 0; i < 4; ++i) {
            const int tr = mb0 + wy * 64 + i * 16 + quad * 4;
            #pragma unroll
            for (int r = 0; r < 4; ++r) {
                const int tg = tr + r;
                const int bh = (tg >> 12) * NH + h;
                float v = acc[i][nn][r] + bias;
                if (isQ) v *= QSC;
                base[((size_t)bh * L_SEQ + (tg & 4095)) * DK + d] = (f16)v;
            }
        }
    }
}

// ---------------------------------------------------------------------------
// Channel-major projection, fp16 MFMA. m = channels (512), n = tokens (8192).
// A = Wh[o][c], B = Bsrc[t][c]. mode 0: V (f16 out, [bh*64+d][t]);
// mode 1: out-proj (fp32 out, [b][o][t]).
// ---------------------------------------------------------------------------
__global__ __launch_bounds__(256) void cproj_mfma(
    const f16* __restrict__ Bsrc, const f16* __restrict__ Wh,
    const float* __restrict__ bias, f16* __restrict__ outV,
    float* __restrict__ outP, int mode)
{
    __shared__ f16 As[128][40];
    __shared__ f16 Bs[128][40];
    const int tid = threadIdx.x;
    const int lane = tid & 63, w = tid >> 6;
    const int l15 = lane & 15, quad = lane >> 4;
    const int wy = w >> 1, wx = w & 1;
    const int n0  = blockIdx.x * 128;   // token tile
    const int mb0 = blockIdx.y * 128;   // channel tile

    f32x4 acc[4][4] = {};
    const int row = tid >> 2, c8 = (tid & 3) * 8;
    const f16* aptr = Wh + (size_t)mb0 * 512;
    const f16* bptr = Bsrc + (size_t)n0 * 512;

    uint4 ga0 = *(const uint4*)(aptr + (size_t)row * 512 + c8);
    uint4 ga1 = *(const uint4*)(aptr + (size_t)(row + 64) * 512 + c8);
    uint4 gb0 = *(const uint4*)(bptr + (size_t)row * 512 + c8);
    uint4 gb1 = *(const uint4*)(bptr + (size_t)(row + 64) * 512 + c8);

    for (int k0 = 0; k0 < 512; k0 += 32) {
        __syncthreads();
        *(uint4*)&As[row][c8] = ga0;
        *(uint4*)&As[row + 64][c8] = ga1;
        *(uint4*)&Bs[row][c8] = gb0;
        *(uint4*)&Bs[row + 64][c8] = gb1;
        if (k0 + 32 < 512) {
            ga0 = *(const uint4*)(aptr + (size_t)row * 512 + k0 + 32 + c8);
            ga1 = *(const uint4*)(aptr + (size_t)(row + 64) * 512 + k0 + 32 + c8);
            gb0 = *(const uint4*)(bptr + (size_t)row * 512 + k0 + 32 + c8);
            gb1 = *(const uint4*)(bptr + (size_t)(row + 64) * 512 + k0 + 32 + c8);
        }
        __syncthreads();
        f16x8 af[4], bf[4];
        #pragma unroll
        for (int i = 0; i < 4; ++i)
            af[i] = *(const f16x8*)&As[wy * 64 + i * 16 + l15][quad * 8];
        #pragma unroll
        for (int n = 0; n < 4; ++n)
            bf[n] = *(const f16x8*)&Bs[wx * 64 + n * 16 + l15][quad * 8];
        #pragma unroll
        for (int i = 0; i < 4; ++i)
            #pragma unroll
            for (int n = 0; n < 4; ++n)
                acc[i][n] = __builtin_amdgcn_mfma_f32_16x16x32_f16(af[i], bf[n], acc[i][n], 0, 0, 0);
    }

    #pragma unroll
    for (int i = 0; i < 4; ++i) {
        #pragma unroll
        for (int r = 0; r < 4; ++r) {
            const int o = mb0 + wy * 64 + i * 16 + quad * 4 + r;   // channel
            const float bv = bias[o];
            #pragma unroll
            for (int nn = 0; nn < 4; ++nn) {
                const int tg = n0 + wx * 64 + nn * 16 + l15;
                const float v = acc[i][nn][r] + bv;
                if (mode == 0) {
                    const int bh = (tg >> 12) * NH + (o >> 6);
                    outV[((size_t)bh * DK + (o & 63)) * L_SEQ + (tg & 4095)] = (f16)v;
                } else {
                    outP[((size_t)(tg >> 12) * C_DIM + o) * L_SEQ + (tg & 4095)] = v;
                }
            }
        }
    }
}

// ---------------------------------------------------------------------------
// Flash attention v9: 32x32x16 MFMA, zero-shuffle P hand-off.
//  * S^T = K·Q with 32x32x16: C layout col=t=lane&31, row(s)=(r&3)+8(r>>2)+4(lane>>5).
//    cvt_pkrtz of C reg pairs yields EXACTLY the PV B-fragment words (col=t,
//    k=8*(lane>>5)+j) -- provided V's k axis is consumed in bit2<->bit3-swapped
//    s order. Softmax + sum_s(P·V) are s-order-invariant, so the swap is baked
//    into the compile-time V column offsets (2x ds_read_b64 per V fragment).
//    No P LDS buffer, no cross-lane ops.
//  * K/V staged HBM->LDS via global_load_lds width 16, double-buffered,
//    ONE barrier per 64-s iter. Bank-XOR swizzle (byte ^= (row&7)<<4) applied
//    by pre-swizzling the per-lane GLOBAL source address (linear LDS dst),
//    same XOR on the read side -> conflict-free ds_read.
//  * LDS 32 KB, VGPR capped 128 -> 4 blocks/CU resident; setprio(1) around
//    MFMA clusters exploits the cross-block phase diversity.
// Partial O stored f16 [half*16+bh][d][t]; l f32 [half*16+bh][t].
// ---------------------------------------------------------------------------
__device__ __forceinline__ void gload_lds16(const char* g, char* l) {
    __builtin_amdgcn_global_load_lds(
        (const __attribute__((address_space(1))) void*)g,
        (__attribute__((address_space(3))) void*)l, 16, 0, 0);
}

__global__ __launch_bounds__(256, 4) void flash16(
    const f16* __restrict__ Qh, const f16* __restrict__ Kh,
    const f16* __restrict__ Vh, f16* __restrict__ Opart,
    float* __restrict__ Lpart)
{
    __shared__ f16 KS[2][64 * 64];     // [buf][s][d]  (cols bank-XOR swizzled)
    __shared__ f16 VS[2][64 * 64];     // [buf][d][s]  (cols bank-XOR swizzled)
    const int tid = threadIdx.x;
    const int lane = tid & 63, w = tid >> 6;
    const int l31 = lane & 31, hl = lane >> 5;
    const int bh = blockIdx.x;          // XCD locality: bh % 8 picks the XCD
    const int t0 = blockIdx.y * 128;
    const int half = blockIdx.z;
    const int s_beg = half * 2048, s_end = s_beg + 2048;
    const int wtb = t0 + w * 32;        // this wave's 32 tokens
    const f16* Qg = Qh + (size_t)bh * L_SEQ * DK;
    const char* Kg = (const char*)(Kh + (size_t)bh * L_SEQ * DK);
    const char* Vg = (const char*)(Vh + (size_t)bh * DK * L_SEQ);

    // persistent Q B-fragments (already scaled by QSC): col=t=l31, k=d
    f16x8 qf[4];
    #pragma unroll
    for (int kst = 0; kst < 4; ++kst)
        qf[kst] = *(const f16x8*)(Qg + (size_t)(wtb + l31) * DK + kst * 16 + hl * 8);

    // staging: 512 16B chunks per 8KB tile; thread covers chunks tid, tid+256.
    // phys slot P: row = P>>7, physcol = P&127; logical col = physcol ^ ((row&7)<<4)
    const int c0 = tid, c1 = tid + 256;
    const int kofs0 = (c0 >> 3) * 128  + (((c0 & 7) * 16) ^ (((c0 >> 3) & 7) << 4));
    const int kofs1 = (c1 >> 3) * 128  + (((c1 & 7) * 16) ^ (((c1 >> 3) & 7) << 4));
    const int vofs0 = (c0 >> 3) * 8192 + (((c0 & 7) * 16) ^ (((c0 >> 3) & 7) << 4));
    const int vofs1 = (c1 >> 3) * 8192 + (((c1 & 7) * 16) ^ (((c1 >> 3) & 7) << 4));
    const int lb0 = (w * 64) * 16, lb1 = (256 + w * 64) * 16;   // wave-uniform LDS bases

    #define STAGE(bufi, s0v) do {                                   \
        const char* kg_ = Kg + (size_t)(s0v) * 128;                 \
        const char* vg_ = Vg + (size_t)(s0v) * 2;                   \
        char* kl_ = (char*)&KS[bufi][0];                            \
        char* vl_ = (char*)&VS[bufi][0];                            \
        gload_lds16(kg_ + kofs0, kl_ + lb0);                        \
        gload_lds16(kg_ + kofs1, kl_ + lb1);                        \
        gload_lds16(vg_ + vofs0, vl_ + lb0);                        \
        gload_lds16(vg_ + vofs1, vl_ + lb1);                        \
    } while (0)

    f32x16 O0 = {}, O1 = {};
    float rs = 0.f;
    h16x2 one2; one2[0] = (__fp16)1.f; one2[1] = (__fp16)1.f;

    STAGE(0, s_beg);
    __syncthreads();

    const int swz = (l31 & 7) << 4;
    const int rowA = l31 * 128, rowB = (32 + l31) * 128;

    int cur = 0;
    for (int s0 = s_beg; s0 < s_end; s0 += 64) {
        if (s0 + 64 < s_end) STAGE(cur ^ 1, s0 + 64);   // issue early, drain at barrier

        const char* Kb = (const char*)&KS[cur][0];
        const char* Vb = (const char*)&VS[cur][0];

        // S^T = K·Q : rows s (2 blocks of 32), cols t
        f32x16 S0 = {}, S1 = {};
        __builtin_amdgcn_s_setprio(1);
        #pragma unroll
        for (int kst = 0; kst < 4; ++kst) {
            const int cb = (kst * 32 + hl * 16) ^ swz;
            const f16x8 k0 = *(const f16x8*)(Kb + rowA + cb);
            const f16x8 k1 = *(const f16x8*)(Kb + rowB + cb);
            S0 = __builtin_amdgcn_mfma_f32_32x32x16_f16(k0, qf[kst], S0, 0, 0, 0);
            S1 = __builtin_amdgcn_mfma_f32_32x32x16_f16(k1, qf[kst], S1, 0, 0, 0);
        }
        __builtin_amdgcn_s_setprio(0);

        // P = exp2(S); pack reg pairs -> PV B-frags directly (own lane)
        union FR { u32 u[4]; f16x8 v; } fr[4];
        #pragma unroll
        for (int q = 0; q < 4; ++q) {
            const h16x2 a01 = __builtin_amdgcn_cvt_pkrtz(
                __builtin_amdgcn_exp2f(S0[4 * q + 0]),
                __builtin_amdgcn_exp2f(S0[4 * q + 1]));
            const h16x2 a23 = __builtin_amdgcn_cvt_pkrtz(
                __builtin_amdgcn_exp2f(S0[4 * q + 2]),
                __builtin_amdgcn_exp2f(S0[4 * q + 3]));
            rs = __builtin_amdgcn_fdot2(a01, one2, rs, false);
            rs = __builtin_amdgcn_fdot2(a23, one2, rs, false);
            union { h16x2 h; u32 u; } p0, p1; p0.h = a01; p1.h = a23;
            fr[q >> 1].u[(q & 1) * 2 + 0] = p0.u;
            fr[q >> 1].u[(q & 1) * 2 + 1] = p1.u;
        }
        #pragma unroll
        for (int q = 0; q < 4; ++q) {
            const h16x2 a01 = __builtin_amdgcn_cvt_pkrtz(
                __builtin_amdgcn_exp2f(S1[4 * q + 0]),
                __builtin_amdgcn_exp2f(S1[4 * q + 1]));
            const h16x2 a23 = __builtin_amdgcn_cvt_pkrtz(
                __builtin_amdgcn_exp2f(S1[4 * q + 2]),
                __builtin_amdgcn_exp2f(S1[4 * q + 3]));
            rs = __builtin_amdgcn_fdot2(a01, one2, rs, false);
            rs = __builtin_amdgcn_fdot2(a23, one2, rs, false);
            union { h16x2 h; u32 u; } p0, p1; p0.h = a01; p1.h = a23;
            fr[2 + (q >> 1)].u[(q & 1) * 2 + 0] = p0.u;
            fr[2 + (q >> 1)].u[(q & 1) * 2 + 1] = p1.u;
        }

        // O += V·P : A = V frag (rows d), k consumed in bit2<->3-swapped s order:
        // elems 0-3: s = kst*16 + 4*hl + j ; elems 4-7: s = kst*16 + 8 + 4*hl + j
        __builtin_amdgcn_s_setprio(1);
        #pragma unroll
        for (int kst = 0; kst < 4; ++kst) {
            const int ca = (kst * 32 + hl * 8) ^ swz;
            const int cb = (kst * 32 + 16 + hl * 8) ^ swz;
            union AV { uint2 d2[2]; f16x8 v; } a0, a1;
            a0.d2[0] = *(const uint2*)(Vb + rowA + ca);
            a0.d2[1] = *(const uint2*)(Vb + rowA + cb);
            a1.d2[0] = *(const uint2*)(Vb + rowB + ca);
            a1.d2[1] = *(const uint2*)(Vb + rowB + cb);
            O0 = __builtin_amdgcn_mfma_f32_32x32x16_f16(a0.v, fr[kst].v, O0, 0, 0, 0);
            O1 = __builtin_amdgcn_mfma_f32_32x32x16_f16(a1.v, fr[kst].v, O1, 0, 0, 0);
        }
        __builtin_amdgcn_s_setprio(0);

        __syncthreads();            // staged tile ready, reads of cur done
        cur ^= 1;
    }
    #undef STAGE

    // l partial: lane pair (l, l+32) covers all s for column t
    rs += __shfl_xor(rs, 32, 64);
    if (lane < 32)
        Lpart[(size_t)(half * 16 + bh) * L_SEQ + wtb + l31] = rs;

    // O partial: row d = mb*32 + (r&3)+8*(r>>2)+4*hl, col t = wtb + l31
    f16* Op = Opart + (size_t)(half * 16 + bh) * DK * L_SEQ;
    #pragma unroll
    for (int r = 0; r < 16; ++r) {
        const int d = (r & 3) + 8 * (r >> 2) + 4 * hl;
        Op[(size_t)d * L_SEQ + wtb + l31] = (f16)O0[r];
        Op[(size_t)(32 + d) * L_SEQ + wtb + l31] = (f16)O1[r];
    }
}

// ---------------------------------------------------------------------------
// combine: O = (Olo + Ohi) / (llo + lhi), transpose [d][t] -> token-major
// f16 [b*4096+t][512] for the out-proj B operand. One block per (bh, 64-t).
// ---------------------------------------------------------------------------
__global__ __launch_bounds__(256) void combine(
    const f16* __restrict__ Opart, const float* __restrict__ Lpart,
    f16* __restrict__ Oh)
{
    __shared__ f16 Ts[64][72];
    __shared__ float Linv[64];
    const int tid = threadIdx.x;
    const int bh = blockIdx.y, b = bh >> 3, h = bh & 7;
    const int t0 = blockIdx.x * 64;
    if (tid < 64) {
        const float lo = Lpart[(size_t)bh * L_SEQ + t0 + tid];
        const float hi = Lpart[(size_t)(16 + bh) * L_SEQ + t0 + tid];
        Linv[tid] = 1.f / (lo + hi);
    }
    __syncthreads();
    const f16* Plo = Opart + (size_t)bh * DK * L_SEQ;
    const f16* Phi = Opart + (size_t)(16 + bh) * DK * L_SEQ;
    const int d = tid >> 4;
    const int tt = (tid & 15) * 4;
    #pragma unroll
    for (int p = 0; p < 4; ++p) {
        const int dd = d + p * 16;
        const size_t off = (size_t)dd * L_SEQ + t0 + tt;
        const f16x4 lo = *(const f16x4*)(Plo + off);
        const f16x4 hi = *(const f16x4*)(Phi + off);
        #pragma unroll
        for (int j = 0; j < 4; ++j)
            Ts[tt + j][dd] = (f16)(((float)lo[j] + (float)hi[j]) * Linv[tt + j]);
    }
    __syncthreads();
    const int tr = tid >> 2, ch = (tid & 3) * 16;
    f16* dst = Oh + ((size_t)(b * L_SEQ + t0 + tr)) * C_DIM + h * DK + ch;
    *(f16x8*)dst = *(const f16x8*)&Ts[tr][ch];
    *(f16x8*)(dst + 8) = *(const f16x8*)&Ts[tr][ch + 8];
}

// ---------------------------------------------------------------------------
extern "C" void kernel_launch(void* const* d_in, const int* in_sizes, int n_in,
                              void* d_out, int out_size, void* d_ws, size_t ws_size,
                              hipStream_t stream) {
    (void)in_sizes; (void)n_in; (void)out_size; (void)ws_size;
    const float* x   = (const float*)d_in[0];
    const float* Wq  = (const float*)d_in[1];
    const float* bq  = (const float*)d_in[2];
    const float* Wkv = (const float*)d_in[3];
    const float* bkv = (const float*)d_in[4];
    const float* Wp  = (const float*)d_in[5];
    const float* bp  = (const float*)d_in[6];
    float* out = (float*)d_out;

    f16* Xt    = (f16*)d_ws;           // [8192][512]
    f16* Wqkh  = Xt + 4194304;         // [1024][512]
    f16* Wvh   = Wqkh + 524288;        // [512][512]
    f16* Wph   = Wvh + 262144;         // [512][512]
    f16* Qh    = Wph + 262144;         // [16][4096][64]
    f16* Kh    = Qh + 4194304;
    f16* Vh    = Kh + 4194304;         // [16*64][4096]
    f16* Oh    = Vh + 4194304;         // [8192][512]
    f16* Opart = Oh + 4194304;         // [2*16][64][4096] f16
    float* Lpart = (float*)(Opart + 8388608);  // [2*16][4096] f32

    prep<<<dim3(128, 1, 3), 256, 0, stream>>>(x, Wq, Wkv, Wp, Xt, Wqkh, Wvh, Wph);
    qk_mfma<<<dim3(64, 8), 256, 0, stream>>>(Xt, Wqkh, bq, bkv, Qh, Kh);
    cproj_mfma<<<dim3(64, 4), 256, 0, stream>>>(Xt, Wvh, bkv + 512, Vh, nullptr, 0);
    flash16<<<dim3(16, 32, 2), 256, 0, stream>>>(Qh, Kh, Vh, Opart, Lpart);
    combine<<<dim3(64, 16), 256, 0, stream>>>(Opart, Lpart, Oh);
    cproj_mfma<<<dim3(64, 4), 256, 0, stream>>>(Oh, Wph, bp, nullptr, out, 1);
}

// Round 4
// 213.570 us; speedup vs baseline: 1.3271x; 1.0144x over previous
//
#include <hip/hip_runtime.h>
#include <math.h>

#define L_SEQ 4096
#define C_DIM 512
#define NH 8
#define DK 64
#define NB 2
#define QSC 0.18033688011112042f  /* (1/sqrt(64)) * log2(e) */

typedef _Float16 f16;
typedef _Float16 f16x8 __attribute__((ext_vector_type(8)));
typedef _Float16 f16x4 __attribute__((ext_vector_type(4)));
typedef __fp16 h16x2 __attribute__((ext_vector_type(2)));   // builtin ABI type
typedef float f32x4 __attribute__((ext_vector_type(4)));
typedef float f32x16 __attribute__((ext_vector_type(16)));
typedef unsigned int u32;

// ---------------------------------------------------------------------------
// prep: z=0,1 -> transpose-cast X[b] [512][4096] fp32 -> Xt [b*4096+t][512] f16
//       z=2   -> plain-cast Wq, Wkv[0:512], Wkv[512:1024], Wp -> f16
// ---------------------------------------------------------------------------
__global__ __launch_bounds__(256) void prep(
    const float* __restrict__ X, const float* __restrict__ Wq,
    const float* __restrict__ Wkv, const float* __restrict__ Wp,
    f16* __restrict__ Xt, f16* __restrict__ Wqkh,
    f16* __restrict__ Wvh, f16* __restrict__ Wph)
{
    const int tid = threadIdx.x;
    const int z = blockIdx.z;
    if (z < 2) {
        __shared__ f16 Ts[64][72];
        const float* src = X + (size_t)z * C_DIM * L_SEQ;
        f16* dst = Xt + (size_t)z * L_SEQ * C_DIM;
        for (int tile = blockIdx.x; tile < 512; tile += gridDim.x) {
            const int c0 = (tile & 7) * 64;
            const int t0 = (tile >> 3) * 64;
            __syncthreads();
            #pragma unroll
            for (int p = 0; p < 4; ++p) {
                const int c = (tid >> 4) + p * 16;
                const int t = (tid & 15) * 4;
                const float4 v = *(const float4*)(src + (size_t)(c0 + c) * L_SEQ + t0 + t);
                Ts[t + 0][c] = (f16)v.x; Ts[t + 1][c] = (f16)v.y;
                Ts[t + 2][c] = (f16)v.z; Ts[t + 3][c] = (f16)v.w;
            }
            __syncthreads();
            #pragma unroll
            for (int p = 0; p < 2; ++p) {
                const int t = (tid >> 3) + p * 32;
                const int ch = (tid & 7) * 8;
                *(f16x8*)(dst + (size_t)(t0 + t) * C_DIM + c0 + ch) =
                    *(const f16x8*)&Ts[t][ch];
            }
        }
    } else {
        const float* srcs[4] = {Wq, Wkv, Wkv + 262144, Wp};
        f16* dsts[4] = {Wqkh, Wqkh + 262144, Wvh, Wph};
        #pragma unroll
        for (int s = 0; s < 4; ++s) {
            const float* sp = srcs[s]; f16* dp = dsts[s];
            for (int i = blockIdx.x * 256 + tid; i < 65536; i += gridDim.x * 256) {
                const float4 v = *(const float4*)(sp + (size_t)i * 4);
                f16x4 h; h[0] = (f16)v.x; h[1] = (f16)v.y; h[2] = (f16)v.z; h[3] = (f16)v.w;
                *(f16x4*)(dp + (size_t)i * 4) = h;
            }
        }
    }
}

// ---------------------------------------------------------------------------
// Q/K projection, fp16 MFMA. m = tokens (global 8192), n = channels (1024).
// A = Xt[t][c], B = Wqkh[o][c]. C row=t, col=o. Q scaled by QSC.
// Outputs token-major Qh/Kh [bh][t][64].
// ---------------------------------------------------------------------------
__global__ __launch_bounds__(256) void qk_mfma(
    const f16* __restrict__ Xt, const f16* __restrict__ Wqkh,
    const float* __restrict__ bq, const float* __restrict__ bkv,
    f16* __restrict__ Qh, f16* __restrict__ Kh)
{
    __shared__ f16 As[128][40];
    __shared__ f16 Bs[128][40];
    const int tid = threadIdx.x;
    const int lane = tid & 63, w = tid >> 6;
    const int l15 = lane & 15, quad = lane >> 4;
    const int wy = w >> 1, wx = w & 1;
    const int mb0 = blockIdx.x * 128;   // token tile
    const int n0  = blockIdx.y * 128;   // channel tile

    f32x4 acc[4][4] = {};
    const int row = tid >> 2, c8 = (tid & 3) * 8;
    const f16* aptr = Xt + (size_t)mb0 * 512;
    const f16* bptr = Wqkh + (size_t)n0 * 512;

    uint4 ga0 = *(const uint4*)(aptr + (size_t)row * 512 + c8);
    uint4 ga1 = *(const uint4*)(aptr + (size_t)(row + 64) * 512 + c8);
    uint4 gb0 = *(const uint4*)(bptr + (size_t)row * 512 + c8);
    uint4 gb1 = *(const uint4*)(bptr + (size_t)(row + 64) * 512 + c8);

    for (int k0 = 0; k0 < 512; k0 += 32) {
        __syncthreads();
        *(uint4*)&As[row][c8] = ga0;
        *(uint4*)&As[row + 64][c8] = ga1;
        *(uint4*)&Bs[row][c8] = gb0;
        *(uint4*)&Bs[row + 64][c8] = gb1;
        if (k0 + 32 < 512) {
            ga0 = *(const uint4*)(aptr + (size_t)row * 512 + k0 + 32 + c8);
            ga1 = *(const uint4*)(aptr + (size_t)(row + 64) * 512 + k0 + 32 + c8);
            gb0 = *(const uint4*)(bptr + (size_t)row * 512 + k0 + 32 + c8);
            gb1 = *(const uint4*)(bptr + (size_t)(row + 64) * 512 + k0 + 32 + c8);
        }
        __syncthreads();
        f16x8 af[4], bf[4];
        #pragma unroll
        for (int i = 0; i < 4; ++i)
            af[i] = *(const f16x8*)&As[wy * 64 + i * 16 + l15][quad * 8];
        #pragma unroll
        for (int n = 0; n < 4; ++n)
            bf[n] = *(const f16x8*)&Bs[wx * 64 + n * 16 + l15][quad * 8];
        #pragma unroll
        for (int i = 0; i < 4; ++i)
            #pragma unroll
            for (int n = 0; n < 4; ++n)
                acc[i][n] = __builtin_amdgcn_mfma_f32_16x16x32_f16(af[i], bf[n], acc[i][n], 0, 0, 0);
    }

    #pragma unroll
    for (int nn = 0; nn < 4; ++nn) {
        const int o = n0 + wx * 64 + nn * 16 + l15;
        const bool isQ = (o < 512);
        const float bias = isQ ? bq[o] : bkv[o - 512];
        const int h = (o & 511) >> 6, d = o & 63;
        f16* base = isQ ? Qh : Kh;
        #pragma unroll
        for (int i = 0; i < 4; ++i) {
            const int tr = mb0 + wy * 64 + i * 16 + quad * 4;
            #pragma unroll
            for (int r = 0; r < 4; ++r) {
                const int tg = tr + r;
                const int bh = (tg >> 12) * NH + h;
                float v = acc[i][nn][r] + bias;
                if (isQ) v *= QSC;
                base[((size_t)bh * L_SEQ + (tg & 4095)) * DK + d] = (f16)v;
            }
        }
    }
}

// ---------------------------------------------------------------------------
// Channel-major projection, fp16 MFMA. m = channels (512), n = tokens (8192).
// A = Wh[o][c], B = Bsrc[t][c]. mode 0: V (f16 out, [bh*64+d][t], with the
// token index bit2<->bit3 PERMUTED so flash16's PV A-fragment reads are
// contiguous b128 in k-order -- see flash16 header); mode 1: out-proj
// (fp32 out, [b][o][t]).
// ---------------------------------------------------------------------------
__global__ __launch_bounds__(256) void cproj_mfma(
    const f16* __restrict__ Bsrc, const f16* __restrict__ Wh,
    const float* __restrict__ bias, f16* __restrict__ outV,
    float* __restrict__ outP, int mode)
{
    __shared__ f16 As[128][40];
    __shared__ f16 Bs[128][40];
    const int tid = threadIdx.x;
    const int lane = tid & 63, w = tid >> 6;
    const int l15 = lane & 15, quad = lane >> 4;
    const int wy = w >> 1, wx = w & 1;
    const int n0  = blockIdx.x * 128;   // token tile
    const int mb0 = blockIdx.y * 128;   // channel tile

    f32x4 acc[4][4] = {};
    const int row = tid >> 2, c8 = (tid & 3) * 8;
    const f16* aptr = Wh + (size_t)mb0 * 512;
    const f16* bptr = Bsrc + (size_t)n0 * 512;

    uint4 ga0 = *(const uint4*)(aptr + (size_t)row * 512 + c8);
    uint4 ga1 = *(const uint4*)(aptr + (size_t)(row + 64) * 512 + c8);
    uint4 gb0 = *(const uint4*)(bptr + (size_t)row * 512 + c8);
    uint4 gb1 = *(const uint4*)(bptr + (size_t)(row + 64) * 512 + c8);

    for (int k0 = 0; k0 < 512; k0 += 32) {
        __syncthreads();
        *(uint4*)&As[row][c8] = ga0;
        *(uint4*)&As[row + 64][c8] = ga1;
        *(uint4*)&Bs[row][c8] = gb0;
        *(uint4*)&Bs[row + 64][c8] = gb1;
        if (k0 + 32 < 512) {
            ga0 = *(const uint4*)(aptr + (size_t)row * 512 + k0 + 32 + c8);
            ga1 = *(const uint4*)(aptr + (size_t)(row + 64) * 512 + k0 + 32 + c8);
            gb0 = *(const uint4*)(bptr + (size_t)row * 512 + k0 + 32 + c8);
            gb1 = *(const uint4*)(bptr + (size_t)(row + 64) * 512 + k0 + 32 + c8);
        }
        __syncthreads();
        f16x8 af[4], bf[4];
        #pragma unroll
        for (int i = 0; i < 4; ++i)
            af[i] = *(const f16x8*)&As[wy * 64 + i * 16 + l15][quad * 8];
        #pragma unroll
        for (int n = 0; n < 4; ++n)
            bf[n] = *(const f16x8*)&Bs[wx * 64 + n * 16 + l15][quad * 8];
        #pragma unroll
        for (int i = 0; i < 4; ++i)
            #pragma unroll
            for (int n = 0; n < 4; ++n)
                acc[i][n] = __builtin_amdgcn_mfma_f32_16x16x32_f16(af[i], bf[n], acc[i][n], 0, 0, 0);
    }

    // token-index low-4-bit permutation for V (swap bits 2 and 3); identity
    // on the t-index used by mode 1.
    const int l15p = (l15 & 3) | ((l15 & 4) << 1) | ((l15 & 8) >> 1);

    #pragma unroll
    for (int i = 0; i < 4; ++i) {
        #pragma unroll
        for (int r = 0; r < 4; ++r) {
            const int o = mb0 + wy * 64 + i * 16 + quad * 4 + r;   // channel
            const float bv = bias[o];
            #pragma unroll
            for (int nn = 0; nn < 4; ++nn) {
                const int tg = n0 + wx * 64 + nn * 16 + l15;
                const float v = acc[i][nn][r] + bv;
                if (mode == 0) {
                    const int tgp = (tg & ~15) | l15p;   // s-permuted store
                    const int bh = (tgp >> 12) * NH + (o >> 6);
                    outV[((size_t)bh * DK + (o & 63)) * L_SEQ + (tgp & 4095)] = (f16)v;
                } else {
                    outP[((size_t)(tg >> 12) * C_DIM + o) * L_SEQ + (tg & 4095)] = v;
                }
            }
        }
    }
}

// ---------------------------------------------------------------------------
// Flash attention v10: 32x32x16 MFMA, zero-shuffle P hand-off, b128-only LDS.
//  * S^T = K·Q with 32x32x16: C layout col=t=lane&31, row(s)=(r&3)+8(r>>2)+4(lane>>5).
//    cvt_pkrtz of C reg pairs yields EXACTLY the PV B-fragment words (col=t,
//    k=8*(lane>>5)+j) under the k->s permutation that swaps bits 2,3 within
//    each 16-chunk. That permutation is baked into Vh's GLOBAL layout at the
//    cproj_mfma write (self-inverse), so the PV A-fragment is a single
//    contiguous ds_read_b128 in k-order -- same conflict-free pattern as the
//    K reads. (v9 used 2x b64 with the swap at read time: 4-way bank
//    conflicts, 12.6M cycles/dispatch.)
//  * K/V staged HBM->LDS via global_load_lds width 16, double-buffered,
//    ONE barrier per 64-s iter. Bank-XOR swizzle (byte ^= (row&7)<<4) applied
//    by pre-swizzling the per-lane GLOBAL source address (linear LDS dst),
//    same XOR on the read side.
//  * LDS 32 KB, VGPR capped -> 4 blocks/CU resident; setprio(1) around
//    MFMA clusters exploits the cross-block phase diversity.
// Partial O stored f16 [half*16+bh][d][t]; l f32 [half*16+bh][t].
// ---------------------------------------------------------------------------
__device__ __forceinline__ void gload_lds16(const char* g, char* l) {
    __builtin_amdgcn_global_load_lds(
        (const __attribute__((address_space(1))) void*)g,
        (__attribute__((address_space(3))) void*)l, 16, 0, 0);
}

__global__ __launch_bounds__(256, 4) void flash16(
    const f16* __restrict__ Qh, const f16* __restrict__ Kh,
    const f16* __restrict__ Vh, f16* __restrict__ Opart,
    float* __restrict__ Lpart)
{
    __shared__ f16 KS[2][64 * 64];     // [buf][s][d]  (cols bank-XOR swizzled)
    __shared__ f16 VS[2][64 * 64];     // [buf][d][kk] (cols bank-XOR swizzled)
    const int tid = threadIdx.x;
    const int lane = tid & 63, w = tid >> 6;
    const int l31 = lane & 31, hl = lane >> 5;
    const int bh = blockIdx.x;          // XCD locality: bh % 8 picks the XCD
    const int t0 = blockIdx.y * 128;
    const int half = blockIdx.z;
    const int s_beg = half * 2048, s_end = s_beg + 2048;
    const int wtb = t0 + w * 32;        // this wave's 32 tokens
    const f16* Qg = Qh + (size_t)bh * L_SEQ * DK;
    const char* Kg = (const char*)(Kh + (size_t)bh * L_SEQ * DK);
    const char* Vg = (const char*)(Vh + (size_t)bh * DK * L_SEQ);

    // persistent Q B-fragments (already scaled by QSC): col=t=l31, k=d
    f16x8 qf[4];
    #pragma unroll
    for (int kst = 0; kst < 4; ++kst)
        qf[kst] = *(const f16x8*)(Qg + (size_t)(wtb + l31) * DK + kst * 16 + hl * 8);

    // staging: 512 16B chunks per 8KB tile; thread covers chunks tid, tid+256.
    // phys slot P: row = P>>7, physcol = P&127; logical col = physcol ^ ((row&7)<<4)
    const int c0 = tid, c1 = tid + 256;
    const int kofs0 = (c0 >> 3) * 128  + (((c0 & 7) * 16) ^ (((c0 >> 3) & 7) << 4));
    const int kofs1 = (c1 >> 3) * 128  + (((c1 & 7) * 16) ^ (((c1 >> 3) & 7) << 4));
    const int vofs0 = (c0 >> 3) * 8192 + (((c0 & 7) * 16) ^ (((c0 >> 3) & 7) << 4));
    const int vofs1 = (c1 >> 3) * 8192 + (((c1 & 7) * 16) ^ (((c1 >> 3) & 7) << 4));
    const int lb0 = (w * 64) * 16, lb1 = (256 + w * 64) * 16;   // wave-uniform LDS bases

    #define STAGE(bufi, s0v) do {                                   \
        const char* kg_ = Kg + (size_t)(s0v) * 128;                 \
        const char* vg_ = Vg + (size_t)(s0v) * 2;                   \
        char* kl_ = (char*)&KS[bufi][0];                            \
        char* vl_ = (char*)&VS[bufi][0];                            \
        gload_lds16(kg_ + kofs0, kl_ + lb0);                        \
        gload_lds16(kg_ + kofs1, kl_ + lb1);                        \
        gload_lds16(vg_ + vofs0, vl_ + lb0);                        \
        gload_lds16(vg_ + vofs1, vl_ + lb1);                        \
    } while (0)

    f32x16 O0 = {}, O1 = {};
    float rs = 0.f;
    h16x2 one2; one2[0] = (__fp16)1.f; one2[1] = (__fp16)1.f;

    STAGE(0, s_beg);
    __syncthreads();

    const int swz = (l31 & 7) << 4;
    const int rowA = l31 * 128, rowB = (32 + l31) * 128;

    int cur = 0;
    for (int s0 = s_beg; s0 < s_end; s0 += 64) {
        if (s0 + 64 < s_end) STAGE(cur ^ 1, s0 + 64);   // issue early, drain at barrier

        const char* Kb = (const char*)&KS[cur][0];
        const char* Vb = (const char*)&VS[cur][0];

        // S^T = K·Q : rows s (2 blocks of 32), cols t
        f32x16 S0 = {}, S1 = {};
        __builtin_amdgcn_s_setprio(1);
        #pragma unroll
        for (int kst = 0; kst < 4; ++kst) {
            const int cb = (kst * 32 + hl * 16) ^ swz;
            const f16x8 k0 = *(const f16x8*)(Kb + rowA + cb);
            const f16x8 k1 = *(const f16x8*)(Kb + rowB + cb);
            S0 = __builtin_amdgcn_mfma_f32_32x32x16_f16(k0, qf[kst], S0, 0, 0, 0);
            S1 = __builtin_amdgcn_mfma_f32_32x32x16_f16(k1, qf[kst], S1, 0, 0, 0);
        }
        __builtin_amdgcn_s_setprio(0);

        // P = exp2(S); pack reg pairs -> PV B-frags directly (own lane)
        union FR { u32 u[4]; f16x8 v; } fr[4];
        #pragma unroll
        for (int q = 0; q < 4; ++q) {
            const h16x2 a01 = __builtin_amdgcn_cvt_pkrtz(
                __builtin_amdgcn_exp2f(S0[4 * q + 0]),
                __builtin_amdgcn_exp2f(S0[4 * q + 1]));
            const h16x2 a23 = __builtin_amdgcn_cvt_pkrtz(
                __builtin_amdgcn_exp2f(S0[4 * q + 2]),
                __builtin_amdgcn_exp2f(S0[4 * q + 3]));
            rs = __builtin_amdgcn_fdot2(a01, one2, rs, false);
            rs = __builtin_amdgcn_fdot2(a23, one2, rs, false);
            union { h16x2 h; u32 u; } p0, p1; p0.h = a01; p1.h = a23;
            fr[q >> 1].u[(q & 1) * 2 + 0] = p0.u;
            fr[q >> 1].u[(q & 1) * 2 + 1] = p1.u;
        }
        #pragma unroll
        for (int q = 0; q < 4; ++q) {
            const h16x2 a01 = __builtin_amdgcn_cvt_pkrtz(
                __builtin_amdgcn_exp2f(S1[4 * q + 0]),
                __builtin_amdgcn_exp2f(S1[4 * q + 1]));
            const h16x2 a23 = __builtin_amdgcn_cvt_pkrtz(
                __builtin_amdgcn_exp2f(S1[4 * q + 2]),
                __builtin_amdgcn_exp2f(S1[4 * q + 3]));
            rs = __builtin_amdgcn_fdot2(a01, one2, rs, false);
            rs = __builtin_amdgcn_fdot2(a23, one2, rs, false);
            union { h16x2 h; u32 u; } p0, p1; p0.h = a01; p1.h = a23;
            fr[2 + (q >> 1)].u[(q & 1) * 2 + 0] = p0.u;
            fr[2 + (q >> 1)].u[(q & 1) * 2 + 1] = p1.u;
        }

        // O += V·P : A = V frag, contiguous b128 in k-order (global layout of
        // Vh is pre-permuted so LDS kk-slot already holds the bit2<->3-swapped s)
        __builtin_amdgcn_s_setprio(1);
        #pragma unroll
        for (int kst = 0; kst < 4; ++kst) {
            const int ca = (kst * 32 + hl * 16) ^ swz;
            const f16x8 v0 = *(const f16x8*)(Vb + rowA + ca);
            const f16x8 v1 = *(const f16x8*)(Vb + rowB + ca);
            O0 = __builtin_amdgcn_mfma_f32_32x32x16_f16(v0, fr[kst].v, O0, 0, 0, 0);
            O1 = __builtin_amdgcn_mfma_f32_32x32x16_f16(v1, fr[kst].v, O1, 0, 0, 0);
        }
        __builtin_amdgcn_s_setprio(0);

        __syncthreads();            // staged tile ready, reads of cur done
        cur ^= 1;
    }
    #undef STAGE

    // l partial: lane pair (l, l+32) covers all s for column t
    rs += __shfl_xor(rs, 32, 64);
    if (lane < 32)
        Lpart[(size_t)(half * 16 + bh) * L_SEQ + wtb + l31] = rs;

    // O partial: row d = mb*32 + (r&3)+8*(r>>2)+4*hl, col t = wtb + l31
    f16* Op = Opart + (size_t)(half * 16 + bh) * DK * L_SEQ;
    #pragma unroll
    for (int r = 0; r < 16; ++r) {
        const int d = (r & 3) + 8 * (r >> 2) + 4 * hl;
        Op[(size_t)d * L_SEQ + wtb + l31] = (f16)O0[r];
        Op[(size_t)(32 + d) * L_SEQ + wtb + l31] = (f16)O1[r];
    }
}

// ---------------------------------------------------------------------------
// combine: O = (Olo + Ohi) / (llo + lhi), transpose [d][t] -> token-major
// f16 [b*4096+t][512] for the out-proj B operand. One block per (bh, 64-t).
// ---------------------------------------------------------------------------
__global__ __launch_bounds__(256) void combine(
    const f16* __restrict__ Opart, const float* __restrict__ Lpart,
    f16* __restrict__ Oh)
{
    __shared__ f16 Ts[64][72];
    __shared__ float Linv[64];
    const int tid = threadIdx.x;
    const int bh = blockIdx.y, b = bh >> 3, h = bh & 7;
    const int t0 = blockIdx.x * 64;
    if (tid < 64) {
        const float lo = Lpart[(size_t)bh * L_SEQ + t0 + tid];
        const float hi = Lpart[(size_t)(16 + bh) * L_SEQ + t0 + tid];
        Linv[tid] = 1.f / (lo + hi);
    }
    __syncthreads();
    const f16* Plo = Opart + (size_t)bh * DK * L_SEQ;
    const f16* Phi = Opart + (size_t)(16 + bh) * DK * L_SEQ;
    const int d = tid >> 4;
    const int tt = (tid & 15) * 4;
    #pragma unroll
    for (int p = 0; p < 4; ++p) {
        const int dd = d + p * 16;
        const size_t off = (size_t)dd * L_SEQ + t0 + tt;
        const f16x4 lo = *(const f16x4*)(Plo + off);
        const f16x4 hi = *(const f16x4*)(Phi + off);
        #pragma unroll
        for (int j = 0; j < 4; ++j)
            Ts[tt + j][dd] = (f16)(((float)lo[j] + (float)hi[j]) * Linv[tt + j]);
    }
    __syncthreads();
    const int tr = tid >> 2, ch = (tid & 3) * 16;
    f16* dst = Oh + ((size_t)(b * L_SEQ + t0 + tr)) * C_DIM + h * DK + ch;
    *(f16x8*)dst = *(const f16x8*)&Ts[tr][ch];
    *(f16x8*)(dst + 8) = *(const f16x8*)&Ts[tr][ch + 8];
}

// ---------------------------------------------------------------------------
extern "C" void kernel_launch(void* const* d_in, const int* in_sizes, int n_in,
                              void* d_out, int out_size, void* d_ws, size_t ws_size,
                              hipStream_t stream) {
    (void)in_sizes; (void)n_in; (void)out_size; (void)ws_size;
    const float* x   = (const float*)d_in[0];
    const float* Wq  = (const float*)d_in[1];
    const float* bq  = (const float*)d_in[2];
    const float* Wkv = (const float*)d_in[3];
    const float* bkv = (const float*)d_in[4];
    const float* Wp  = (const float*)d_in[5];
    const float* bp  = (const float*)d_in[6];
    float* out = (float*)d_out;

    f16* Xt    = (f16*)d_ws;           // [8192][512]
    f16* Wqkh  = Xt + 4194304;         // [1024][512]
    f16* Wvh   = Wqkh + 524288;        // [512][512]
    f16* Wph   = Wvh + 262144;         // [512][512]
    f16* Qh    = Wph + 262144;         // [16][4096][64]
    f16* Kh    = Qh + 4194304;
    f16* Vh    = Kh + 4194304;         // [16*64][4096] (token idx bit2<->3 permuted)
    f16* Oh    = Vh + 4194304;         // [8192][512]
    f16* Opart = Oh + 4194304;         // [2*16][64][4096] f16
    float* Lpart = (float*)(Opart + 8388608);  // [2*16][4096] f32

    prep<<<dim3(128, 1, 3), 256, 0, stream>>>(x, Wq, Wkv, Wp, Xt, Wqkh, Wvh, Wph);
    qk_mfma<<<dim3(64, 8), 256, 0, stream>>>(Xt, Wqkh, bq, bkv, Qh, Kh);
    cproj_mfma<<<dim3(64, 4), 256, 0, stream>>>(Xt, Wvh, bkv + 512, Vh, nullptr, 0);
    flash16<<<dim3(16, 32, 2), 256, 0, stream>>>(Qh, Kh, Vh, Opart, Lpart);
    combine<<<dim3(64, 16), 256, 0, stream>>>(Opart, Lpart, Oh);
    cproj_mfma<<<dim3(64, 4), 256, 0, stream>>>(Oh, Wph, bp, nullptr, out, 1);
}

// Round 5
// 205.333 us; speedup vs baseline: 1.3804x; 1.0401x over previous
//
#include <hip/hip_runtime.h>
#include <math.h>

#define L_SEQ 4096
#define C_DIM 512
#define NH 8
#define DK 64
#define NB 2
#define QSC 0.18033688011112042f  /* (1/sqrt(64)) * log2(e) */

typedef _Float16 f16;
typedef _Float16 f16x8 __attribute__((ext_vector_type(8)));
typedef _Float16 f16x4 __attribute__((ext_vector_type(4)));
typedef __fp16 h16x2 __attribute__((ext_vector_type(2)));   // builtin ABI type
typedef float f32x4 __attribute__((ext_vector_type(4)));
typedef float f32x16 __attribute__((ext_vector_type(16)));
typedef unsigned int u32;

// ---------------------------------------------------------------------------
// prep: z=0,1 -> transpose-cast X[b] [512][4096] fp32 -> Xt [b*4096+t][512] f16
//       z=2   -> plain-cast Wq, Wkv[0:512], Wkv[512:1024], Wp -> f16
// ---------------------------------------------------------------------------
__global__ __launch_bounds__(256) void prep(
    const float* __restrict__ X, const float* __restrict__ Wq,
    const float* __restrict__ Wkv, const float* __restrict__ Wp,
    f16* __restrict__ Xt, f16* __restrict__ Wqkh,
    f16* __restrict__ Wvh, f16* __restrict__ Wph)
{
    const int tid = threadIdx.x;
    const int z = blockIdx.z;
    if (z < 2) {
        __shared__ f16 Ts[64][72];
        const float* src = X + (size_t)z * C_DIM * L_SEQ;
        f16* dst = Xt + (size_t)z * L_SEQ * C_DIM;
        for (int tile = blockIdx.x; tile < 512; tile += gridDim.x) {
            const int c0 = (tile & 7) * 64;
            const int t0 = (tile >> 3) * 64;
            __syncthreads();
            #pragma unroll
            for (int p = 0; p < 4; ++p) {
                const int c = (tid >> 4) + p * 16;
                const int t = (tid & 15) * 4;
                const float4 v = *(const float4*)(src + (size_t)(c0 + c) * L_SEQ + t0 + t);
                Ts[t + 0][c] = (f16)v.x; Ts[t + 1][c] = (f16)v.y;
                Ts[t + 2][c] = (f16)v.z; Ts[t + 3][c] = (f16)v.w;
            }
            __syncthreads();
            #pragma unroll
            for (int p = 0; p < 2; ++p) {
                const int t = (tid >> 3) + p * 32;
                const int ch = (tid & 7) * 8;
                *(f16x8*)(dst + (size_t)(t0 + t) * C_DIM + c0 + ch) =
                    *(const f16x8*)&Ts[t][ch];
            }
        }
    } else {
        const float* srcs[4] = {Wq, Wkv, Wkv + 262144, Wp};
        f16* dsts[4] = {Wqkh, Wqkh + 262144, Wvh, Wph};
        #pragma unroll
        for (int s = 0; s < 4; ++s) {
            const float* sp = srcs[s]; f16* dp = dsts[s];
            for (int i = blockIdx.x * 256 + tid; i < 65536; i += gridDim.x * 256) {
                const float4 v = *(const float4*)(sp + (size_t)i * 4);
                f16x4 h; h[0] = (f16)v.x; h[1] = (f16)v.y; h[2] = (f16)v.z; h[3] = (f16)v.w;
                *(f16x4*)(dp + (size_t)i * 4) = h;
            }
        }
    }
}

// ---------------------------------------------------------------------------
// Q/K projection, fp16 MFMA. m = tokens (global 8192), n = channels (1024).
// A = Xt[t][c], B = Wqkh[o][c]. C row=t, col=o. Q scaled by QSC.
// Outputs token-major Qh/Kh [bh][t][64].
// ---------------------------------------------------------------------------
__global__ __launch_bounds__(256) void qk_mfma(
    const f16* __restrict__ Xt, const f16* __restrict__ Wqkh,
    const float* __restrict__ bq, const float* __restrict__ bkv,
    f16* __restrict__ Qh, f16* __restrict__ Kh)
{
    __shared__ f16 As[128][40];
    __shared__ f16 Bs[128][40];
    const int tid = threadIdx.x;
    const int lane = tid & 63, w = tid >> 6;
    const int l15 = lane & 15, quad = lane >> 4;
    const int wy = w >> 1, wx = w & 1;
    const int mb0 = blockIdx.x * 128;   // token tile
    const int n0  = blockIdx.y * 128;   // channel tile

    f32x4 acc[4][4] = {};
    const int row = tid >> 2, c8 = (tid & 3) * 8;
    const f16* aptr = Xt + (size_t)mb0 * 512;
    const f16* bptr = Wqkh + (size_t)n0 * 512;

    uint4 ga0 = *(const uint4*)(aptr + (size_t)row * 512 + c8);
    uint4 ga1 = *(const uint4*)(aptr + (size_t)(row + 64) * 512 + c8);
    uint4 gb0 = *(const uint4*)(bptr + (size_t)row * 512 + c8);
    uint4 gb1 = *(const uint4*)(bptr + (size_t)(row + 64) * 512 + c8);

    for (int k0 = 0; k0 < 512; k0 += 32) {
        __syncthreads();
        *(uint4*)&As[row][c8] = ga0;
        *(uint4*)&As[row + 64][c8] = ga1;
        *(uint4*)&Bs[row][c8] = gb0;
        *(uint4*)&Bs[row + 64][c8] = gb1;
        if (k0 + 32 < 512) {
            ga0 = *(const uint4*)(aptr + (size_t)row * 512 + k0 + 32 + c8);
            ga1 = *(const uint4*)(aptr + (size_t)(row + 64) * 512 + k0 + 32 + c8);
            gb0 = *(const uint4*)(bptr + (size_t)row * 512 + k0 + 32 + c8);
            gb1 = *(const uint4*)(bptr + (size_t)(row + 64) * 512 + k0 + 32 + c8);
        }
        __syncthreads();
        f16x8 af[4], bf[4];
        #pragma unroll
        for (int i = 0; i < 4; ++i)
            af[i] = *(const f16x8*)&As[wy * 64 + i * 16 + l15][quad * 8];
        #pragma unroll
        for (int n = 0; n < 4; ++n)
            bf[n] = *(const f16x8*)&Bs[wx * 64 + n * 16 + l15][quad * 8];
        #pragma unroll
        for (int i = 0; i < 4; ++i)
            #pragma unroll
            for (int n = 0; n < 4; ++n)
                acc[i][n] = __builtin_amdgcn_mfma_f32_16x16x32_f16(af[i], bf[n], acc[i][n], 0, 0, 0);
    }

    #pragma unroll
    for (int nn = 0; nn < 4; ++nn) {
        const int o = n0 + wx * 64 + nn * 16 + l15;
        const bool isQ = (o < 512);
        const float bias = isQ ? bq[o] : bkv[o - 512];
        const int h = (o & 511) >> 6, d = o & 63;
        f16* base = isQ ? Qh : Kh;
        #pragma unroll
        for (int i = 0; i < 4; ++i) {
            const int tr = mb0 + wy * 64 + i * 16 + quad * 4;
            #pragma unroll
            for (int r = 0; r < 4; ++r) {
                const int tg = tr + r;
                const int bh = (tg >> 12) * NH + h;
                float v = acc[i][nn][r] + bias;
                if (isQ) v *= QSC;
                base[((size_t)bh * L_SEQ + (tg & 4095)) * DK + d] = (f16)v;
            }
        }
    }
}

// ---------------------------------------------------------------------------
// Channel-major projection, fp16 MFMA. m = channels (512), n = tokens (8192).
// A = Wh[o][c], B = Bsrc[t][c]. mode 0: V (f16 out, [bh*64+d][t], with the
// token index bit2<->bit3 PERMUTED so flash16's PV A-fragment reads are
// contiguous b128 in k-order -- see flash16 header); mode 1: out-proj
// (fp32 out, [b][o][t]).
// ---------------------------------------------------------------------------
__global__ __launch_bounds__(256) void cproj_mfma(
    const f16* __restrict__ Bsrc, const f16* __restrict__ Wh,
    const float* __restrict__ bias, f16* __restrict__ outV,
    float* __restrict__ outP, int mode)
{
    __shared__ f16 As[128][40];
    __shared__ f16 Bs[128][40];
    const int tid = threadIdx.x;
    const int lane = tid & 63, w = tid >> 6;
    const int l15 = lane & 15, quad = lane >> 4;
    const int wy = w >> 1, wx = w & 1;
    const int n0  = blockIdx.x * 128;   // token tile
    const int mb0 = blockIdx.y * 128;   // channel tile

    f32x4 acc[4][4] = {};
    const int row = tid >> 2, c8 = (tid & 3) * 8;
    const f16* aptr = Wh + (size_t)mb0 * 512;
    const f16* bptr = Bsrc + (size_t)n0 * 512;

    uint4 ga0 = *(const uint4*)(aptr + (size_t)row * 512 + c8);
    uint4 ga1 = *(const uint4*)(aptr + (size_t)(row + 64) * 512 + c8);
    uint4 gb0 = *(const uint4*)(bptr + (size_t)row * 512 + c8);
    uint4 gb1 = *(const uint4*)(bptr + (size_t)(row + 64) * 512 + c8);

    for (int k0 = 0; k0 < 512; k0 += 32) {
        __syncthreads();
        *(uint4*)&As[row][c8] = ga0;
        *(uint4*)&As[row + 64][c8] = ga1;
        *(uint4*)&Bs[row][c8] = gb0;
        *(uint4*)&Bs[row + 64][c8] = gb1;
        if (k0 + 32 < 512) {
            ga0 = *(const uint4*)(aptr + (size_t)row * 512 + k0 + 32 + c8);
            ga1 = *(const uint4*)(aptr + (size_t)(row + 64) * 512 + k0 + 32 + c8);
            gb0 = *(const uint4*)(bptr + (size_t)row * 512 + k0 + 32 + c8);
            gb1 = *(const uint4*)(bptr + (size_t)(row + 64) * 512 + k0 + 32 + c8);
        }
        __syncthreads();
        f16x8 af[4], bf[4];
        #pragma unroll
        for (int i = 0; i < 4; ++i)
            af[i] = *(const f16x8*)&As[wy * 64 + i * 16 + l15][quad * 8];
        #pragma unroll
        for (int n = 0; n < 4; ++n)
            bf[n] = *(const f16x8*)&Bs[wx * 64 + n * 16 + l15][quad * 8];
        #pragma unroll
        for (int i = 0; i < 4; ++i)
            #pragma unroll
            for (int n = 0; n < 4; ++n)
                acc[i][n] = __builtin_amdgcn_mfma_f32_16x16x32_f16(af[i], bf[n], acc[i][n], 0, 0, 0);
    }

    // token-index low-4-bit permutation for V (swap bits 2 and 3); identity
    // on the t-index used by mode 1.
    const int l15p = (l15 & 3) | ((l15 & 4) << 1) | ((l15 & 8) >> 1);

    #pragma unroll
    for (int i = 0; i < 4; ++i) {
        #pragma unroll
        for (int r = 0; r < 4; ++r) {
            const int o = mb0 + wy * 64 + i * 16 + quad * 4 + r;   // channel
            const float bv = bias[o];
            #pragma unroll
            for (int nn = 0; nn < 4; ++nn) {
                const int tg = n0 + wx * 64 + nn * 16 + l15;
                const float v = acc[i][nn][r] + bv;
                if (mode == 0) {
                    const int tgp = (tg & ~15) | l15p;   // s-permuted store
                    const int bh = (tgp >> 12) * NH + (o >> 6);
                    outV[((size_t)bh * DK + (o & 63)) * L_SEQ + (tgp & 4095)] = (f16)v;
                } else {
                    outP[((size_t)(tg >> 12) * C_DIM + o) * L_SEQ + (tg & 4095)] = v;
                }
            }
        }
    }
}

// ---------------------------------------------------------------------------
// Flash attention v11: 32x32x16 MFMA, zero-shuffle P hand-off, 64-token waves.
//  * Each wave owns TWO 32-token column blocks. K/V A-fragments are identical
//    for both t-blocks, so each ds_read_b128 feeds TWO MFMAs: 16 reads ->
//    32 MFMAs per wave-iter (v10 was 16->16). Halves per-CU LDS read volume,
//    which was the busiest pipe (~57%: 2.097M b128 reads x ~12cyc incl. the
//    intrinsic +4cyc/read counted as SQ_LDS_BANK_CONFLICT).
//  * S^T = K·Q; C layout col=t=lane&31, row(s)=(r&3)+8(r>>2)+4(lane>>5).
//    cvt_pkrtz of C reg pairs gives the PV B-fragment words directly; the
//    k->s bit2<->3 permutation is baked into Vh's global layout (cproj).
//  * K/V staged HBM->LDS via global_load_lds width 16, double-buffered,
//    ONE barrier per 64-s iter; bank-XOR swizzle via pre-swizzled global src.
//  * 512 blocks (grid.y=16) = 2 blocks/CU; __launch_bounds__(256,2) caps
//    VGPR at 256 (~230 predicted: 4x f32x16 O + transient 4x f32x16 S +
//    8 Q frags + 2 fr sets).
// Partial O stored f16 [half*16+bh][d][t]; l f32 [half*16+bh][t].
// ---------------------------------------------------------------------------
__device__ __forceinline__ void gload_lds16(const char* g, char* l) {
    __builtin_amdgcn_global_load_lds(
        (const __attribute__((address_space(1))) void*)g,
        (__attribute__((address_space(3))) void*)l, 16, 0, 0);
}

__global__ __launch_bounds__(256, 2) void flash16(
    const f16* __restrict__ Qh, const f16* __restrict__ Kh,
    const f16* __restrict__ Vh, f16* __restrict__ Opart,
    float* __restrict__ Lpart)
{
    __shared__ f16 KS[2][64 * 64];     // [buf][s][d]  (cols bank-XOR swizzled)
    __shared__ f16 VS[2][64 * 64];     // [buf][d][kk] (cols bank-XOR swizzled)
    const int tid = threadIdx.x;
    const int lane = tid & 63, w = tid >> 6;
    const int l31 = lane & 31, hl = lane >> 5;
    const int bh = blockIdx.x;          // XCD locality: bh % 8 picks the XCD
    const int t0 = blockIdx.y * 256;
    const int half = blockIdx.z;
    const int s_beg = half * 2048, s_end = s_beg + 2048;
    const int wtb = t0 + w * 64;        // this wave's 64 tokens (2 x 32)
    const f16* Qg = Qh + (size_t)bh * L_SEQ * DK;
    const char* Kg = (const char*)(Kh + (size_t)bh * L_SEQ * DK);
    const char* Vg = (const char*)(Vh + (size_t)bh * DK * L_SEQ);

    // persistent Q B-fragments (already scaled by QSC): col=t, k=d
    f16x8 qf0[4], qf1[4];
    #pragma unroll
    for (int kst = 0; kst < 4; ++kst) {
        qf0[kst] = *(const f16x8*)(Qg + (size_t)(wtb + l31) * DK + kst * 16 + hl * 8);
        qf1[kst] = *(const f16x8*)(Qg + (size_t)(wtb + 32 + l31) * DK + kst * 16 + hl * 8);
    }

    // staging: 512 16B chunks per 8KB tile; thread covers chunks tid, tid+256.
    const int c0 = tid, c1 = tid + 256;
    const int kofs0 = (c0 >> 3) * 128  + (((c0 & 7) * 16) ^ (((c0 >> 3) & 7) << 4));
    const int kofs1 = (c1 >> 3) * 128  + (((c1 & 7) * 16) ^ (((c1 >> 3) & 7) << 4));
    const int vofs0 = (c0 >> 3) * 8192 + (((c0 & 7) * 16) ^ (((c0 >> 3) & 7) << 4));
    const int vofs1 = (c1 >> 3) * 8192 + (((c1 & 7) * 16) ^ (((c1 >> 3) & 7) << 4));
    const int lb0 = (w * 64) * 16, lb1 = (256 + w * 64) * 16;   // wave-uniform LDS bases

    #define STAGE(bufi, s0v) do {                                   \
        const char* kg_ = Kg + (size_t)(s0v) * 128;                 \
        const char* vg_ = Vg + (size_t)(s0v) * 2;                   \
        char* kl_ = (char*)&KS[bufi][0];                            \
        char* vl_ = (char*)&VS[bufi][0];                            \
        gload_lds16(kg_ + kofs0, kl_ + lb0);                        \
        gload_lds16(kg_ + kofs1, kl_ + lb1);                        \
        gload_lds16(vg_ + vofs0, vl_ + lb0);                        \
        gload_lds16(vg_ + vofs1, vl_ + lb1);                        \
    } while (0)

    f32x16 O00 = {}, O01 = {}, O10 = {}, O11 = {};   // [d-blk][t-blk]
    float rs0 = 0.f, rs1 = 0.f;
    h16x2 one2; one2[0] = (__fp16)1.f; one2[1] = (__fp16)1.f;

    STAGE(0, s_beg);
    __syncthreads();

    const int swz = (l31 & 7) << 4;
    const int rowA = l31 * 128, rowB = (32 + l31) * 128;

    int cur = 0;
    for (int s0 = s_beg; s0 < s_end; s0 += 64) {
        if (s0 + 64 < s_end) STAGE(cur ^ 1, s0 + 64);   // issue early, drain at barrier

        const char* Kb = (const char*)&KS[cur][0];
        const char* Vb = (const char*)&VS[cur][0];

        // S^T = K·Q : one K read feeds both t-blocks
        f32x16 Sa0 = {}, Sa1 = {}, Sb0 = {}, Sb1 = {};   // [s-blk][t-blk]
        __builtin_amdgcn_s_setprio(1);
        #pragma unroll
        for (int kst = 0; kst < 4; ++kst) {
            const int cb = (kst * 32 + hl * 16) ^ swz;
            const f16x8 k0 = *(const f16x8*)(Kb + rowA + cb);
            const f16x8 k1 = *(const f16x8*)(Kb + rowB + cb);
            Sa0 = __builtin_amdgcn_mfma_f32_32x32x16_f16(k0, qf0[kst], Sa0, 0, 0, 0);
            Sa1 = __builtin_amdgcn_mfma_f32_32x32x16_f16(k0, qf1[kst], Sa1, 0, 0, 0);
            Sb0 = __builtin_amdgcn_mfma_f32_32x32x16_f16(k1, qf0[kst], Sb0, 0, 0, 0);
            Sb1 = __builtin_amdgcn_mfma_f32_32x32x16_f16(k1, qf1[kst], Sb1, 0, 0, 0);
        }
        __builtin_amdgcn_s_setprio(0);

        // P = exp2(S); pack reg pairs -> PV B-frags directly (own lane)
        union FR { u32 u[4]; f16x8 v; } fr0[4], fr1[4];
        #pragma unroll
        for (int q = 0; q < 4; ++q) {
            const h16x2 a01 = __builtin_amdgcn_cvt_pkrtz(
                __builtin_amdgcn_exp2f(Sa0[4 * q + 0]),
                __builtin_amdgcn_exp2f(Sa0[4 * q + 1]));
            const h16x2 a23 = __builtin_amdgcn_cvt_pkrtz(
                __builtin_amdgcn_exp2f(Sa0[4 * q + 2]),
                __builtin_amdgcn_exp2f(Sa0[4 * q + 3]));
            rs0 = __builtin_amdgcn_fdot2(a01, one2, rs0, false);
            rs0 = __builtin_amdgcn_fdot2(a23, one2, rs0, false);
            union { h16x2 h; u32 u; } p0, p1; p0.h = a01; p1.h = a23;
            fr0[q >> 1].u[(q & 1) * 2 + 0] = p0.u;
            fr0[q >> 1].u[(q & 1) * 2 + 1] = p1.u;
        }
        #pragma unroll
        for (int q = 0; q < 4; ++q) {
            const h16x2 a01 = __builtin_amdgcn_cvt_pkrtz(
                __builtin_amdgcn_exp2f(Sb0[4 * q + 0]),
                __builtin_amdgcn_exp2f(Sb0[4 * q + 1]));
            const h16x2 a23 = __builtin_amdgcn_cvt_pkrtz(
                __builtin_amdgcn_exp2f(Sb0[4 * q + 2]),
                __builtin_amdgcn_exp2f(Sb0[4 * q + 3]));
            rs0 = __builtin_amdgcn_fdot2(a01, one2, rs0, false);
            rs0 = __builtin_amdgcn_fdot2(a23, one2, rs0, false);
            union { h16x2 h; u32 u; } p0, p1; p0.h = a01; p1.h = a23;
            fr0[2 + (q >> 1)].u[(q & 1) * 2 + 0] = p0.u;
            fr0[2 + (q >> 1)].u[(q & 1) * 2 + 1] = p1.u;
        }
        #pragma unroll
        for (int q = 0; q < 4; ++q) {
            const h16x2 a01 = __builtin_amdgcn_cvt_pkrtz(
                __builtin_amdgcn_exp2f(Sa1[4 * q + 0]),
                __builtin_amdgcn_exp2f(Sa1[4 * q + 1]));
            const h16x2 a23 = __builtin_amdgcn_cvt_pkrtz(
                __builtin_amdgcn_exp2f(Sa1[4 * q + 2]),
                __builtin_amdgcn_exp2f(Sa1[4 * q + 3]));
            rs1 = __builtin_amdgcn_fdot2(a01, one2, rs1, false);
            rs1 = __builtin_amdgcn_fdot2(a23, one2, rs1, false);
            union { h16x2 h; u32 u; } p0, p1; p0.h = a01; p1.h = a23;
            fr1[q >> 1].u[(q & 1) * 2 + 0] = p0.u;
            fr1[q >> 1].u[(q & 1) * 2 + 1] = p1.u;
        }
        #pragma unroll
        for (int q = 0; q < 4; ++q) {
            const h16x2 a01 = __builtin_amdgcn_cvt_pkrtz(
                __builtin_amdgcn_exp2f(Sb1[4 * q + 0]),
                __builtin_amdgcn_exp2f(Sb1[4 * q + 1]));
            const h16x2 a23 = __builtin_amdgcn_cvt_pkrtz(
                __builtin_amdgcn_exp2f(Sb1[4 * q + 2]),
                __builtin_amdgcn_exp2f(Sb1[4 * q + 3]));
            rs1 = __builtin_amdgcn_fdot2(a01, one2, rs1, false);
            rs1 = __builtin_amdgcn_fdot2(a23, one2, rs1, false);
            union { h16x2 h; u32 u; } p0, p1; p0.h = a01; p1.h = a23;
            fr1[2 + (q >> 1)].u[(q & 1) * 2 + 0] = p0.u;
            fr1[2 + (q >> 1)].u[(q & 1) * 2 + 1] = p1.u;
        }

        // O += V·P : one V read feeds both t-blocks (Vh globally pre-permuted)
        __builtin_amdgcn_s_setprio(1);
        #pragma unroll
        for (int kst = 0; kst < 4; ++kst) {
            const int ca = (kst * 32 + hl * 16) ^ swz;
            const f16x8 v0 = *(const f16x8*)(Vb + rowA + ca);
            const f16x8 v1 = *(const f16x8*)(Vb + rowB + ca);
            O00 = __builtin_amdgcn_mfma_f32_32x32x16_f16(v0, fr0[kst].v, O00, 0, 0, 0);
            O01 = __builtin_amdgcn_mfma_f32_32x32x16_f16(v0, fr1[kst].v, O01, 0, 0, 0);
            O10 = __builtin_amdgcn_mfma_f32_32x32x16_f16(v1, fr0[kst].v, O10, 0, 0, 0);
            O11 = __builtin_amdgcn_mfma_f32_32x32x16_f16(v1, fr1[kst].v, O11, 0, 0, 0);
        }
        __builtin_amdgcn_s_setprio(0);

        __syncthreads();            // staged tile ready, reads of cur done
        cur ^= 1;
    }
    #undef STAGE

    // l partial: lane pair (l, l+32) covers all s for column t
    rs0 += __shfl_xor(rs0, 32, 64);
    rs1 += __shfl_xor(rs1, 32, 64);
    if (lane < 32) {
        float* Lp = Lpart + (size_t)(half * 16 + bh) * L_SEQ + wtb;
        Lp[l31] = rs0;
        Lp[32 + l31] = rs1;
    }

    // O partial: row d = db*32 + (r&3)+8*(r>>2)+4*hl, col t = wtb + tb*32 + l31
    f16* Op = Opart + (size_t)(half * 16 + bh) * DK * L_SEQ;
    #pragma unroll
    for (int r = 0; r < 16; ++r) {
        const int d = (r & 3) + 8 * (r >> 2) + 4 * hl;
        Op[(size_t)d * L_SEQ + wtb + l31] = (f16)O00[r];
        Op[(size_t)d * L_SEQ + wtb + 32 + l31] = (f16)O01[r];
        Op[(size_t)(32 + d) * L_SEQ + wtb + l31] = (f16)O10[r];
        Op[(size_t)(32 + d) * L_SEQ + wtb + 32 + l31] = (f16)O11[r];
    }
}

// ---------------------------------------------------------------------------
// combine: O = (Olo + Ohi) / (llo + lhi), transpose [d][t] -> token-major
// f16 [b*4096+t][512] for the out-proj B operand. One block per (bh, 64-t).
// ---------------------------------------------------------------------------
__global__ __launch_bounds__(256) void combine(
    const f16* __restrict__ Opart, const float* __restrict__ Lpart,
    f16* __restrict__ Oh)
{
    __shared__ f16 Ts[64][72];
    __shared__ float Linv[64];
    const int tid = threadIdx.x;
    const int bh = blockIdx.y, b = bh >> 3, h = bh & 7;
    const int t0 = blockIdx.x * 64;
    if (tid < 64) {
        const float lo = Lpart[(size_t)bh * L_SEQ + t0 + tid];
        const float hi = Lpart[(size_t)(16 + bh) * L_SEQ + t0 + tid];
        Linv[tid] = 1.f / (lo + hi);
    }
    __syncthreads();
    const f16* Plo = Opart + (size_t)bh * DK * L_SEQ;
    const f16* Phi = Opart + (size_t)(16 + bh) * DK * L_SEQ;
    const int d = tid >> 4;
    const int tt = (tid & 15) * 4;
    #pragma unroll
    for (int p = 0; p < 4; ++p) {
        const int dd = d + p * 16;
        const size_t off = (size_t)dd * L_SEQ + t0 + tt;
        const f16x4 lo = *(const f16x4*)(Plo + off);
        const f16x4 hi = *(const f16x4*)(Phi + off);
        #pragma unroll
        for (int j = 0; j < 4; ++j)
            Ts[tt + j][dd] = (f16)(((float)lo[j] + (float)hi[j]) * Linv[tt + j]);
    }
    __syncthreads();
    const int tr = tid >> 2, ch = (tid & 3) * 16;
    f16* dst = Oh + ((size_t)(b * L_SEQ + t0 + tr)) * C_DIM + h * DK + ch;
    *(f16x8*)dst = *(const f16x8*)&Ts[tr][ch];
    *(f16x8*)(dst + 8) = *(const f16x8*)&Ts[tr][ch + 8];
}

// ---------------------------------------------------------------------------
extern "C" void kernel_launch(void* const* d_in, const int* in_sizes, int n_in,
                              void* d_out, int out_size, void* d_ws, size_t ws_size,
                              hipStream_t stream) {
    (void)in_sizes; (void)n_in; (void)out_size; (void)ws_size;
    const float* x   = (const float*)d_in[0];
    const float* Wq  = (const float*)d_in[1];
    const float* bq  = (const float*)d_in[2];
    const float* Wkv = (const float*)d_in[3];
    const float* bkv = (const float*)d_in[4];
    const float* Wp  = (const float*)d_in[5];
    const float* bp  = (const float*)d_in[6];
    float* out = (float*)d_out;

    f16* Xt    = (f16*)d_ws;           // [8192][512]
    f16* Wqkh  = Xt + 4194304;         // [1024][512]
    f16* Wvh   = Wqkh + 524288;        // [512][512]
    f16* Wph   = Wvh + 262144;         // [512][512]
    f16* Qh    = Wph + 262144;         // [16][4096][64]
    f16* Kh    = Qh + 4194304;
    f16* Vh    = Kh + 4194304;         // [16*64][4096] (token idx bit2<->3 permuted)
    f16* Oh    = Vh + 4194304;         // [8192][512]
    f16* Opart = Oh + 4194304;         // [2*16][64][4096] f16
    float* Lpart = (float*)(Opart + 8388608);  // [2*16][4096] f32

    prep<<<dim3(128, 1, 3), 256, 0, stream>>>(x, Wq, Wkv, Wp, Xt, Wqkh, Wvh, Wph);
    qk_mfma<<<dim3(64, 8), 256, 0, stream>>>(Xt, Wqkh, bq, bkv, Qh, Kh);
    cproj_mfma<<<dim3(64, 4), 256, 0, stream>>>(Xt, Wvh, bkv + 512, Vh, nullptr, 0);
    flash16<<<dim3(16, 16, 2), 256, 0, stream>>>(Qh, Kh, Vh, Opart, Lpart);
    combine<<<dim3(64, 16), 256, 0, stream>>>(Opart, Lpart, Oh);
    cproj_mfma<<<dim3(64, 4), 256, 0, stream>>>(Oh, Wph, bp, nullptr, out, 1);
}

// Round 6
// 203.386 us; speedup vs baseline: 1.3936x; 1.0096x over previous
//
#include <hip/hip_runtime.h>
#include <math.h>

#define L_SEQ 4096
#define C_DIM 512
#define NH 8
#define DK 64
#define NB 2
#define QSC 0.18033688011112042f  /* (1/sqrt(64)) * log2(e) */

typedef _Float16 f16;
typedef _Float16 f16x8 __attribute__((ext_vector_type(8)));
typedef _Float16 f16x4 __attribute__((ext_vector_type(4)));
typedef __fp16 h16x2 __attribute__((ext_vector_type(2)));   // builtin ABI type
typedef float f32x4 __attribute__((ext_vector_type(4)));
typedef float f32x16 __attribute__((ext_vector_type(16)));
typedef unsigned int u32;

// ---------------------------------------------------------------------------
// prep: z=0,1 -> transpose-cast X[b] [512][4096] fp32 -> Xt [b*4096+t][512] f16
//       z=2   -> plain-cast Wq, Wkv[0:512], Wkv[512:1024], Wp -> f16
// ---------------------------------------------------------------------------
__global__ __launch_bounds__(256) void prep(
    const float* __restrict__ X, const float* __restrict__ Wq,
    const float* __restrict__ Wkv, const float* __restrict__ Wp,
    f16* __restrict__ Xt, f16* __restrict__ Wqkh,
    f16* __restrict__ Wvh, f16* __restrict__ Wph)
{
    const int tid = threadIdx.x;
    const int z = blockIdx.z;
    if (z < 2) {
        __shared__ f16 Ts[64][72];
        const float* src = X + (size_t)z * C_DIM * L_SEQ;
        f16* dst = Xt + (size_t)z * L_SEQ * C_DIM;
        for (int tile = blockIdx.x; tile < 512; tile += gridDim.x) {
            const int c0 = (tile & 7) * 64;
            const int t0 = (tile >> 3) * 64;
            __syncthreads();
            #pragma unroll
            for (int p = 0; p < 4; ++p) {
                const int c = (tid >> 4) + p * 16;
                const int t = (tid & 15) * 4;
                const float4 v = *(const float4*)(src + (size_t)(c0 + c) * L_SEQ + t0 + t);
                Ts[t + 0][c] = (f16)v.x; Ts[t + 1][c] = (f16)v.y;
                Ts[t + 2][c] = (f16)v.z; Ts[t + 3][c] = (f16)v.w;
            }
            __syncthreads();
            #pragma unroll
            for (int p = 0; p < 2; ++p) {
                const int t = (tid >> 3) + p * 32;
                const int ch = (tid & 7) * 8;
                *(f16x8*)(dst + (size_t)(t0 + t) * C_DIM + c0 + ch) =
                    *(const f16x8*)&Ts[t][ch];
            }
        }
    } else {
        const float* srcs[4] = {Wq, Wkv, Wkv + 262144, Wp};
        f16* dsts[4] = {Wqkh, Wqkh + 262144, Wvh, Wph};
        #pragma unroll
        for (int s = 0; s < 4; ++s) {
            const float* sp = srcs[s]; f16* dp = dsts[s];
            for (int i = blockIdx.x * 256 + tid; i < 65536; i += gridDim.x * 256) {
                const float4 v = *(const float4*)(sp + (size_t)i * 4);
                f16x4 h; h[0] = (f16)v.x; h[1] = (f16)v.y; h[2] = (f16)v.z; h[3] = (f16)v.w;
                *(f16x4*)(dp + (size_t)i * 4) = h;
            }
        }
    }
}

// ---------------------------------------------------------------------------
// Q/K projection, fp16 MFMA. m = tokens (global 8192), n = channels (1024).
// A = Xt[t][c], B = Wqkh[o][c]. C row=t, col=o. Q scaled by QSC.
// Outputs token-major Qh/Kh [bh][t][64].
// ---------------------------------------------------------------------------
__global__ __launch_bounds__(256) void qk_mfma(
    const f16* __restrict__ Xt, const f16* __restrict__ Wqkh,
    const float* __restrict__ bq, const float* __restrict__ bkv,
    f16* __restrict__ Qh, f16* __restrict__ Kh)
{
    __shared__ f16 As[128][40];
    __shared__ f16 Bs[128][40];
    const int tid = threadIdx.x;
    const int lane = tid & 63, w = tid >> 6;
    const int l15 = lane & 15, quad = lane >> 4;
    const int wy = w >> 1, wx = w & 1;
    const int mb0 = blockIdx.x * 128;   // token tile
    const int n0  = blockIdx.y * 128;   // channel tile

    f32x4 acc[4][4] = {};
    const int row = tid >> 2, c8 = (tid & 3) * 8;
    const f16* aptr = Xt + (size_t)mb0 * 512;
    const f16* bptr = Wqkh + (size_t)n0 * 512;

    uint4 ga0 = *(const uint4*)(aptr + (size_t)row * 512 + c8);
    uint4 ga1 = *(const uint4*)(aptr + (size_t)(row + 64) * 512 + c8);
    uint4 gb0 = *(const uint4*)(bptr + (size_t)row * 512 + c8);
    uint4 gb1 = *(const uint4*)(bptr + (size_t)(row + 64) * 512 + c8);

    for (int k0 = 0; k0 < 512; k0 += 32) {
        __syncthreads();
        *(uint4*)&As[row][c8] = ga0;
        *(uint4*)&As[row + 64][c8] = ga1;
        *(uint4*)&Bs[row][c8] = gb0;
        *(uint4*)&Bs[row + 64][c8] = gb1;
        if (k0 + 32 < 512) {
            ga0 = *(const uint4*)(aptr + (size_t)row * 512 + k0 + 32 + c8);
            ga1 = *(const uint4*)(aptr + (size_t)(row + 64) * 512 + k0 + 32 + c8);
            gb0 = *(const uint4*)(bptr + (size_t)row * 512 + k0 + 32 + c8);
            gb1 = *(const uint4*)(bptr + (size_t)(row + 64) * 512 + k0 + 32 + c8);
        }
        __syncthreads();
        f16x8 af[4], bf[4];
        #pragma unroll
        for (int i = 0; i < 4; ++i)
            af[i] = *(const f16x8*)&As[wy * 64 + i * 16 + l15][quad * 8];
        #pragma unroll
        for (int n = 0; n < 4; ++n)
            bf[n] = *(const f16x8*)&Bs[wx * 64 + n * 16 + l15][quad * 8];
        #pragma unroll
        for (int i = 0; i < 4; ++i)
            #pragma unroll
            for (int n = 0; n < 4; ++n)
                acc[i][n] = __builtin_amdgcn_mfma_f32_16x16x32_f16(af[i], bf[n], acc[i][n], 0, 0, 0);
    }

    #pragma unroll
    for (int nn = 0; nn < 4; ++nn) {
        const int o = n0 + wx * 64 + nn * 16 + l15;
        const bool isQ = (o < 512);
        const float bias = isQ ? bq[o] : bkv[o - 512];
        const int h = (o & 511) >> 6, d = o & 63;
        f16* base = isQ ? Qh : Kh;
        #pragma unroll
        for (int i = 0; i < 4; ++i) {
            const int tr = mb0 + wy * 64 + i * 16 + quad * 4;
            #pragma unroll
            for (int r = 0; r < 4; ++r) {
                const int tg = tr + r;
                const int bh = (tg >> 12) * NH + h;
                float v = acc[i][nn][r] + bias;
                if (isQ) v *= QSC;
                base[((size_t)bh * L_SEQ + (tg & 4095)) * DK + d] = (f16)v;
            }
        }
    }
}

// ---------------------------------------------------------------------------
// Channel-major projection, fp16 MFMA. m = channels (512), n = tokens (8192).
// A = Wh[o][c], B = Bsrc[t][c]. mode 0: V (f16 out, [bh*64+d][t], with the
// token index bit2<->bit3 PERMUTED so flash16's PV A-fragment reads are
// contiguous b128 in k-order -- see flash16 header); mode 1: out-proj
// (fp32 out, [b][o][t]).
// ---------------------------------------------------------------------------
__global__ __launch_bounds__(256) void cproj_mfma(
    const f16* __restrict__ Bsrc, const f16* __restrict__ Wh,
    const float* __restrict__ bias, f16* __restrict__ outV,
    float* __restrict__ outP, int mode)
{
    __shared__ f16 As[128][40];
    __shared__ f16 Bs[128][40];
    const int tid = threadIdx.x;
    const int lane = tid & 63, w = tid >> 6;
    const int l15 = lane & 15, quad = lane >> 4;
    const int wy = w >> 1, wx = w & 1;
    const int n0  = blockIdx.x * 128;   // token tile
    const int mb0 = blockIdx.y * 128;   // channel tile

    f32x4 acc[4][4] = {};
    const int row = tid >> 2, c8 = (tid & 3) * 8;
    const f16* aptr = Wh + (size_t)mb0 * 512;
    const f16* bptr = Bsrc + (size_t)n0 * 512;

    uint4 ga0 = *(const uint4*)(aptr + (size_t)row * 512 + c8);
    uint4 ga1 = *(const uint4*)(aptr + (size_t)(row + 64) * 512 + c8);
    uint4 gb0 = *(const uint4*)(bptr + (size_t)row * 512 + c8);
    uint4 gb1 = *(const uint4*)(bptr + (size_t)(row + 64) * 512 + c8);

    for (int k0 = 0; k0 < 512; k0 += 32) {
        __syncthreads();
        *(uint4*)&As[row][c8] = ga0;
        *(uint4*)&As[row + 64][c8] = ga1;
        *(uint4*)&Bs[row][c8] = gb0;
        *(uint4*)&Bs[row + 64][c8] = gb1;
        if (k0 + 32 < 512) {
            ga0 = *(const uint4*)(aptr + (size_t)row * 512 + k0 + 32 + c8);
            ga1 = *(const uint4*)(aptr + (size_t)(row + 64) * 512 + k0 + 32 + c8);
            gb0 = *(const uint4*)(bptr + (size_t)row * 512 + k0 + 32 + c8);
            gb1 = *(const uint4*)(bptr + (size_t)(row + 64) * 512 + k0 + 32 + c8);
        }
        __syncthreads();
        f16x8 af[4], bf[4];
        #pragma unroll
        for (int i = 0; i < 4; ++i)
            af[i] = *(const f16x8*)&As[wy * 64 + i * 16 + l15][quad * 8];
        #pragma unroll
        for (int n = 0; n < 4; ++n)
            bf[n] = *(const f16x8*)&Bs[wx * 64 + n * 16 + l15][quad * 8];
        #pragma unroll
        for (int i = 0; i < 4; ++i)
            #pragma unroll
            for (int n = 0; n < 4; ++n)
                acc[i][n] = __builtin_amdgcn_mfma_f32_16x16x32_f16(af[i], bf[n], acc[i][n], 0, 0, 0);
    }

    // token-index low-4-bit permutation for V (swap bits 2 and 3); identity
    // on the t-index used by mode 1.
    const int l15p = (l15 & 3) | ((l15 & 4) << 1) | ((l15 & 8) >> 1);

    #pragma unroll
    for (int i = 0; i < 4; ++i) {
        #pragma unroll
        for (int r = 0; r < 4; ++r) {
            const int o = mb0 + wy * 64 + i * 16 + quad * 4 + r;   // channel
            const float bv = bias[o];
            #pragma unroll
            for (int nn = 0; nn < 4; ++nn) {
                const int tg = n0 + wx * 64 + nn * 16 + l15;
                const float v = acc[i][nn][r] + bv;
                if (mode == 0) {
                    const int tgp = (tg & ~15) | l15p;   // s-permuted store
                    const int bh = (tgp >> 12) * NH + (o >> 6);
                    outV[((size_t)bh * DK + (o & 63)) * L_SEQ + (tgp & 4095)] = (f16)v;
                } else {
                    outP[((size_t)(tg >> 12) * C_DIM + o) * L_SEQ + (tg & 4095)] = v;
                }
            }
        }
    }
}

// ---------------------------------------------------------------------------
// Flash attention v12: PV-deferred software pipeline (T15-lite).
//  * v11 post-mortem: MfmaUtil 35 + VALUBusy 37 + LDS ~25 ~= serial pipes;
//    2 waves/SIMD (reg-limited: ~228/512 per wave) can't hide the in-wave
//    chain ds_read->QK->softmax->ds_read->PV->barrier.
//  * v12: at iter i issue QK(i) then PV(i-1) (fr held in regs, one tile back).
//    PV is independent of QK(i) results -> matrix pipe sees 32 back-to-back
//    MFMAs while softmax(i) runs on the VALU pipe. Epilogue does PV(31).
//  * V triple-buffered in LDS (stage (i+1)%3, PV reads (i-1)%3 -- disjoint);
//    K stays double-buffered. LDS 40KB -> still 2 blocks/CU.
//  * S accumulators halved (32 AGPR): Sa computed+softmaxed, then Sb reuses
//    the regs (sched_barrier(0) pins the order) -- pays for the 2nd fr set.
//  * fr ping-pong via 2x-unrolled loop with named frA/frB (no runtime idx).
// Partial O stored f16 [half*16+bh][d][t]; l f32 [half*16+bh][t].
// ---------------------------------------------------------------------------
__device__ __forceinline__ void gload_lds16(const char* g, char* l) {
    __builtin_amdgcn_global_load_lds(
        (const __attribute__((address_space(1))) void*)g,
        (__attribute__((address_space(3))) void*)l, 16, 0, 0);
}

union FR { u32 u[4]; f16x8 v; };

__device__ __forceinline__ void smax8(const f32x16& S, FR* fr, int base,
                                      float& rsv, h16x2 one2) {
    #pragma unroll
    for (int q = 0; q < 4; ++q) {
        const h16x2 a01 = __builtin_amdgcn_cvt_pkrtz(
            __builtin_amdgcn_exp2f(S[4 * q + 0]),
            __builtin_amdgcn_exp2f(S[4 * q + 1]));
        const h16x2 a23 = __builtin_amdgcn_cvt_pkrtz(
            __builtin_amdgcn_exp2f(S[4 * q + 2]),
            __builtin_amdgcn_exp2f(S[4 * q + 3]));
        rsv = __builtin_amdgcn_fdot2(a01, one2, rsv, false);
        rsv = __builtin_amdgcn_fdot2(a23, one2, rsv, false);
        union { h16x2 h; u32 u; } p0, p1; p0.h = a01; p1.h = a23;
        fr[base + (q >> 1)].u[(q & 1) * 2 + 0] = p0.u;
        fr[base + (q >> 1)].u[(q & 1) * 2 + 1] = p1.u;
    }
}

__global__ __launch_bounds__(256, 2) void flash16(
    const f16* __restrict__ Qh, const f16* __restrict__ Kh,
    const f16* __restrict__ Vh, f16* __restrict__ Opart,
    float* __restrict__ Lpart)
{
    __shared__ f16 KS[2][4096];        // [buf][s][d]  (cols bank-XOR swizzled)
    __shared__ f16 VS[3][4096];        // [buf][d][kk] (cols bank-XOR swizzled)
    const int tid = threadIdx.x;
    const int lane = tid & 63, w = tid >> 6;
    const int l31 = lane & 31, hl = lane >> 5;
    const int bh = blockIdx.x;          // XCD locality: bh % 8 picks the XCD
    const int t0 = blockIdx.y * 256;
    const int half = blockIdx.z;
    const int s_beg = half * 2048;
    const int wtb = t0 + w * 64;        // this wave's 64 tokens (2 x 32)
    const f16* Qg = Qh + (size_t)bh * L_SEQ * DK;
    const char* Kg = (const char*)(Kh + (size_t)bh * L_SEQ * DK);
    const char* Vg = (const char*)(Vh + (size_t)bh * DK * L_SEQ);

    // persistent Q B-fragments (already scaled by QSC): col=t, k=d
    f16x8 qf0[4], qf1[4];
    #pragma unroll
    for (int kst = 0; kst < 4; ++kst) {
        qf0[kst] = *(const f16x8*)(Qg + (size_t)(wtb + l31) * DK + kst * 16 + hl * 8);
        qf1[kst] = *(const f16x8*)(Qg + (size_t)(wtb + 32 + l31) * DK + kst * 16 + hl * 8);
    }

    // staging: 512 16B chunks per 8KB tile; thread covers chunks tid, tid+256.
    const int c0 = tid, c1 = tid + 256;
    const int kofs0 = (c0 >> 3) * 128  + (((c0 & 7) * 16) ^ (((c0 >> 3) & 7) << 4));
    const int kofs1 = (c1 >> 3) * 128  + (((c1 & 7) * 16) ^ (((c1 >> 3) & 7) << 4));
    const int vofs0 = (c0 >> 3) * 8192 + (((c0 & 7) * 16) ^ (((c0 >> 3) & 7) << 4));
    const int vofs1 = (c1 >> 3) * 8192 + (((c1 & 7) * 16) ^ (((c1 >> 3) & 7) << 4));
    const int lb0 = (w * 64) * 16, lb1 = (256 + w * 64) * 16;   // wave-uniform LDS bases

    #define STAGE_K(kb, s0v) do {                                    \
        const char* kg_ = Kg + (size_t)(s0v) * 128;                  \
        char* kl_ = (char*)&KS[kb][0];                               \
        gload_lds16(kg_ + kofs0, kl_ + lb0);                         \
        gload_lds16(kg_ + kofs1, kl_ + lb1);                         \
    } while (0)
    #define STAGE_V(vOfs, s0v) do {                                  \
        const char* vg_ = Vg + (size_t)(s0v) * 2;                    \
        char* vl_ = (char*)&VS[0][0] + (vOfs);                       \
        gload_lds16(vg_ + vofs0, vl_ + lb0);                         \
        gload_lds16(vg_ + vofs1, vl_ + lb1);                         \
    } while (0)

    f32x16 O00 = {}, O01 = {}, O10 = {}, O11 = {};   // [d-blk][t-blk]
    float rs0 = 0.f, rs1 = 0.f;
    h16x2 one2; one2[0] = (__fp16)1.f; one2[1] = (__fp16)1.f;
    FR frA0[4], frA1[4], frB0[4], frB1[4];

    STAGE_K(0, s_beg); STAGE_V(0, s_beg);
    __syncthreads();

    const int swz = (l31 & 7) << 4;
    const int rowA = l31 * 128, rowB = (32 + l31) * 128;

    // one iteration: stage(i+1), QK-A, softmax-A, QK-B + PV(i-1), softmax-B
    #define QKBODY(s0v, kbR, kbS, DOSTG, DOPV, stO, pvO, frC0, frC1, frP0, frP1) do { \
        if (DOSTG) { STAGE_K(kbS, (s0v) + 64); STAGE_V(stO, (s0v) + 64); }  \
        const char* Kb = (const char*)&KS[kbR][0];                          \
        f16x8 kf[4];                                                        \
        _Pragma("unroll")                                                   \
        for (int kst = 0; kst < 4; ++kst)                                   \
            kf[kst] = *(const f16x8*)(Kb + rowA + ((kst * 32 + hl * 16) ^ swz)); \
        {                                                                   \
            f32x16 Sa0 = {}, Sa1 = {};                                      \
            __builtin_amdgcn_s_setprio(1);                                  \
            _Pragma("unroll")                                               \
            for (int kst = 0; kst < 4; ++kst) {                             \
                Sa0 = __builtin_amdgcn_mfma_f32_32x32x16_f16(kf[kst], qf0[kst], Sa0, 0, 0, 0); \
                Sa1 = __builtin_amdgcn_mfma_f32_32x32x16_f16(kf[kst], qf1[kst], Sa1, 0, 0, 0); \
            }                                                               \
            __builtin_amdgcn_s_setprio(0);                                  \
            _Pragma("unroll")                                               \
            for (int kst = 0; kst < 4; ++kst)                               \
                kf[kst] = *(const f16x8*)(Kb + rowB + ((kst * 32 + hl * 16) ^ swz)); \
            smax8(Sa0, frC0, 0, rs0, one2);                                 \
            smax8(Sa1, frC1, 0, rs1, one2);                                 \
        }                                                                   \
        __builtin_amdgcn_sched_barrier(0);                                  \
        {                                                                   \
            f32x16 Sb0 = {}, Sb1 = {};                                      \
            __builtin_amdgcn_s_setprio(1);                                  \
            _Pragma("unroll")                                               \
            for (int kst = 0; kst < 4; ++kst) {                             \
                Sb0 = __builtin_amdgcn_mfma_f32_32x32x16_f16(kf[kst], qf0[kst], Sb0, 0, 0, 0); \
                Sb1 = __builtin_amdgcn_mfma_f32_32x32x16_f16(kf[kst], qf1[kst], Sb1, 0, 0, 0); \
            }                                                               \
            if (DOPV) {                                                     \
                const char* Vb = (const char*)&VS[0][0] + (pvO);            \
                _Pragma("unroll")                                           \
                for (int kst = 0; kst < 4; ++kst) {                         \
                    const int ca = (kst * 32 + hl * 16) ^ swz;              \
                    const f16x8 v0 = *(const f16x8*)(Vb + rowA + ca);       \
                    const f16x8 v1 = *(const f16x8*)(Vb + rowB + ca);       \
                    O00 = __builtin_amdgcn_mfma_f32_32x32x16_f16(v0, frP0[kst].v, O00, 0, 0, 0); \
                    O01 = __builtin_amdgcn_mfma_f32_32x32x16_f16(v0, frP1[kst].v, O01, 0, 0, 0); \
                    O10 = __builtin_amdgcn_mfma_f32_32x32x16_f16(v1, frP0[kst].v, O10, 0, 0, 0); \
                    O11 = __builtin_amdgcn_mfma_f32_32x32x16_f16(v1, frP1[kst].v, O11, 0, 0, 0); \
                }                                                           \
            }                                                               \
            __builtin_amdgcn_s_setprio(0);                                  \
            smax8(Sb0, frC0, 2, rs0, one2);                                 \
            smax8(Sb1, frC1, 2, rs1, one2);                                 \
        }                                                                   \
        __syncthreads();                                                    \
    } while (0)

    // it = 0: cur fr = A, no PV; stages tile1 -> KS[1], VS[1]
    QKBODY(s_beg, 0, 1, true, false, 8192, 0, frA0, frA1, frB0, frB1);

    int s0 = s_beg + 64;
    int stO = 16384, pvO = 0;   // it1: stage tile2 -> VS[2]; PV(0) -> VS[0]
    #pragma unroll 1
    for (int p = 0; p < 15; ++p) {
        // odd it: read KS[1], stage KS[0]; cur=frB, prev=frA
        QKBODY(s0, 1, 0, true, true, stO, pvO, frB0, frB1, frA0, frA1);
        s0 += 64; stO = (stO == 16384) ? 0 : stO + 8192; pvO = (pvO == 16384) ? 0 : pvO + 8192;
        // even it: read KS[0], stage KS[1]; cur=frA, prev=frB
        QKBODY(s0, 0, 1, true, true, stO, pvO, frA0, frA1, frB0, frB1);
        s0 += 64; stO = (stO == 16384) ? 0 : stO + 8192; pvO = (pvO == 16384) ? 0 : pvO + 8192;
    }
    // it = 31 (odd): last tile, no stage; PV(30) from VS[0]
    QKBODY(s0, 1, 0, false, true, 0, pvO, frB0, frB1, frA0, frA1);

    // epilogue: PV(31) -- tile31 lives in VS[31%3 = 1], fr in frB
    {
        const char* Vb = (const char*)&VS[0][0] + 8192;
        __builtin_amdgcn_s_setprio(1);
        #pragma unroll
        for (int kst = 0; kst < 4; ++kst) {
            const int ca = (kst * 32 + hl * 16) ^ swz;
            const f16x8 v0 = *(const f16x8*)(Vb + rowA + ca);
            const f16x8 v1 = *(const f16x8*)(Vb + rowB + ca);
            O00 = __builtin_amdgcn_mfma_f32_32x32x16_f16(v0, frB0[kst].v, O00, 0, 0, 0);
            O01 = __builtin_amdgcn_mfma_f32_32x32x16_f16(v0, frB1[kst].v, O01, 0, 0, 0);
            O10 = __builtin_amdgcn_mfma_f32_32x32x16_f16(v1, frB0[kst].v, O10, 0, 0, 0);
            O11 = __builtin_amdgcn_mfma_f32_32x32x16_f16(v1, frB1[kst].v, O11, 0, 0, 0);
        }
        __builtin_amdgcn_s_setprio(0);
    }
    #undef QKBODY
    #undef STAGE_K
    #undef STAGE_V

    // l partial: lane pair (l, l+32) covers all s for column t
    rs0 += __shfl_xor(rs0, 32, 64);
    rs1 += __shfl_xor(rs1, 32, 64);
    if (lane < 32) {
        float* Lp = Lpart + (size_t)(half * 16 + bh) * L_SEQ + wtb;
        Lp[l31] = rs0;
        Lp[32 + l31] = rs1;
    }

    // O partial: row d = db*32 + (r&3)+8*(r>>2)+4*hl, col t = wtb + tb*32 + l31
    f16* Op = Opart + (size_t)(half * 16 + bh) * DK * L_SEQ;
    #pragma unroll
    for (int r = 0; r < 16; ++r) {
        const int d = (r & 3) + 8 * (r >> 2) + 4 * hl;
        Op[(size_t)d * L_SEQ + wtb + l31] = (f16)O00[r];
        Op[(size_t)d * L_SEQ + wtb + 32 + l31] = (f16)O01[r];
        Op[(size_t)(32 + d) * L_SEQ + wtb + l31] = (f16)O10[r];
        Op[(size_t)(32 + d) * L_SEQ + wtb + 32 + l31] = (f16)O11[r];
    }
}

// ---------------------------------------------------------------------------
// combine: O = (Olo + Ohi) / (llo + lhi), transpose [d][t] -> token-major
// f16 [b*4096+t][512] for the out-proj B operand. One block per (bh, 64-t).
// ---------------------------------------------------------------------------
__global__ __launch_bounds__(256) void combine(
    const f16* __restrict__ Opart, const float* __restrict__ Lpart,
    f16* __restrict__ Oh)
{
    __shared__ f16 Ts[64][72];
    __shared__ float Linv[64];
    const int tid = threadIdx.x;
    const int bh = blockIdx.y, b = bh >> 3, h = bh & 7;
    const int t0 = blockIdx.x * 64;
    if (tid < 64) {
        const float lo = Lpart[(size_t)bh * L_SEQ + t0 + tid];
        const float hi = Lpart[(size_t)(16 + bh) * L_SEQ + t0 + tid];
        Linv[tid] = 1.f / (lo + hi);
    }
    __syncthreads();
    const f16* Plo = Opart + (size_t)bh * DK * L_SEQ;
    const f16* Phi = Opart + (size_t)(16 + bh) * DK * L_SEQ;
    const int d = tid >> 4;
    const int tt = (tid & 15) * 4;
    #pragma unroll
    for (int p = 0; p < 4; ++p) {
        const int dd = d + p * 16;
        const size_t off = (size_t)dd * L_SEQ + t0 + tt;
        const f16x4 lo = *(const f16x4*)(Plo + off);
        const f16x4 hi = *(const f16x4*)(Phi + off);
        #pragma unroll
        for (int j = 0; j < 4; ++j)
            Ts[tt + j][dd] = (f16)(((float)lo[j] + (float)hi[j]) * Linv[tt + j]);
    }
    __syncthreads();
    const int tr = tid >> 2, ch = (tid & 3) * 16;
    f16* dst = Oh + ((size_t)(b * L_SEQ + t0 + tr)) * C_DIM + h * DK + ch;
    *(f16x8*)dst = *(const f16x8*)&Ts[tr][ch];
    *(f16x8*)(dst + 8) = *(const f16x8*)&Ts[tr][ch + 8];
}

// ---------------------------------------------------------------------------
extern "C" void kernel_launch(void* const* d_in, const int* in_sizes, int n_in,
                              void* d_out, int out_size, void* d_ws, size_t ws_size,
                              hipStream_t stream) {
    (void)in_sizes; (void)n_in; (void)out_size; (void)ws_size;
    const float* x   = (const float*)d_in[0];
    const float* Wq  = (const float*)d_in[1];
    const float* bq  = (const float*)d_in[2];
    const float* Wkv = (const float*)d_in[3];
    const float* bkv = (const float*)d_in[4];
    const float* Wp  = (const float*)d_in[5];
    const float* bp  = (const float*)d_in[6];
    float* out = (float*)d_out;

    f16* Xt    = (f16*)d_ws;           // [8192][512]
    f16* Wqkh  = Xt + 4194304;         // [1024][512]
    f16* Wvh   = Wqkh + 524288;        // [512][512]
    f16* Wph   = Wvh + 262144;         // [512][512]
    f16* Qh    = Wph + 262144;         // [16][4096][64]
    f16* Kh    = Qh + 4194304;
    f16* Vh    = Kh + 4194304;         // [16*64][4096] (token idx bit2<->3 permuted)
    f16* Oh    = Vh + 4194304;         // [8192][512]
    f16* Opart = Oh + 4194304;         // [2*16][64][4096] f16
    float* Lpart = (float*)(Opart + 8388608);  // [2*16][4096] f32

    prep<<<dim3(128, 1, 3), 256, 0, stream>>>(x, Wq, Wkv, Wp, Xt, Wqkh, Wvh, Wph);
    qk_mfma<<<dim3(64, 8), 256, 0, stream>>>(Xt, Wqkh, bq, bkv, Qh, Kh);
    cproj_mfma<<<dim3(64, 4), 256, 0, stream>>>(Xt, Wvh, bkv + 512, Vh, nullptr, 0);
    flash16<<<dim3(16, 16, 2), 256, 0, stream>>>(Qh, Kh, Vh, Opart, Lpart);
    combine<<<dim3(64, 16), 256, 0, stream>>>(Opart, Lpart, Oh);
    cproj_mfma<<<dim3(64, 4), 256, 0, stream>>>(Oh, Wph, bp, nullptr, out, 1);
}

// Round 9
// 200.465 us; speedup vs baseline: 1.4139x; 1.0146x over previous
//
#include <hip/hip_runtime.h>
#include <math.h>

#define L_SEQ 4096
#define C_DIM 512
#define NH 8
#define DK 64
#define NB 2
#define QSC 0.18033688011112042f  /* (1/sqrt(64)) * log2(e) */

typedef _Float16 f16;
typedef _Float16 f16x8 __attribute__((ext_vector_type(8)));
typedef _Float16 f16x4 __attribute__((ext_vector_type(4)));
typedef __fp16 h16x2 __attribute__((ext_vector_type(2)));   // builtin ABI type
typedef float f32x4 __attribute__((ext_vector_type(4)));
typedef float f32x16 __attribute__((ext_vector_type(16)));
typedef unsigned int u32;

// ---------------------------------------------------------------------------
// prep: z=0,1 -> transpose-cast X[b] [512][4096] fp32 -> Xt [b*4096+t][512] f16
//       z=2   -> plain-cast Wq, Wkv[0:512], Wkv[512:1024], Wp -> f16
// (Wq, Wk, Wv land contiguously as Wqkv [1536][512] for the fused projection.)
// ---------------------------------------------------------------------------
__global__ __launch_bounds__(256) void prep(
    const float* __restrict__ X, const float* __restrict__ Wq,
    const float* __restrict__ Wkv, const float* __restrict__ Wp,
    f16* __restrict__ Xt, f16* __restrict__ Wqkh,
    f16* __restrict__ Wvh, f16* __restrict__ Wph)
{
    const int tid = threadIdx.x;
    const int z = blockIdx.z;
    if (z < 2) {
        __shared__ f16 Ts[64][72];
        const float* src = X + (size_t)z * C_DIM * L_SEQ;
        f16* dst = Xt + (size_t)z * L_SEQ * C_DIM;
        for (int tile = blockIdx.x; tile < 512; tile += gridDim.x) {
            const int c0 = (tile & 7) * 64;
            const int t0 = (tile >> 3) * 64;
            __syncthreads();
            #pragma unroll
            for (int p = 0; p < 4; ++p) {
                const int c = (tid >> 4) + p * 16;
                const int t = (tid & 15) * 4;
                const float4 v = *(const float4*)(src + (size_t)(c0 + c) * L_SEQ + t0 + t);
                Ts[t + 0][c] = (f16)v.x; Ts[t + 1][c] = (f16)v.y;
                Ts[t + 2][c] = (f16)v.z; Ts[t + 3][c] = (f16)v.w;
            }
            __syncthreads();
            #pragma unroll
            for (int p = 0; p < 2; ++p) {
                const int t = (tid >> 3) + p * 32;
                const int ch = (tid & 7) * 8;
                *(f16x8*)(dst + (size_t)(t0 + t) * C_DIM + c0 + ch) =
                    *(const f16x8*)&Ts[t][ch];
            }
        }
    } else {
        const float* srcs[4] = {Wq, Wkv, Wkv + 262144, Wp};
        f16* dsts[4] = {Wqkh, Wqkh + 262144, Wvh, Wph};
        #pragma unroll
        for (int s = 0; s < 4; ++s) {
            const float* sp = srcs[s]; f16* dp = dsts[s];
            for (int i = blockIdx.x * 256 + tid; i < 65536; i += gridDim.x * 256) {
                const float4 v = *(const float4*)(sp + (size_t)i * 4);
                f16x4 h; h[0] = (f16)v.x; h[1] = (f16)v.y; h[2] = (f16)v.z; h[3] = (f16)v.w;
                *(f16x4*)(dp + (size_t)i * 4) = h;
            }
        }
    }
}

// ---------------------------------------------------------------------------
// Fused Q/K/V projection, fp16 MFMA. m = tokens (8192), n = channels (1536).
// A = Xt[t][c], B = Wqkv[o][c] (Wq,Wk,Wv contiguous). C row=t, col=o.
//  o <  512: Q (bias bq, xQSC) -> Qh token-major [bh][t][64]
//  o < 1024: K (bias bkv)      -> Kh token-major
//  o >=1024: V (bias bkv[512+c]) -> Vh channel-major [bh][d][t'] with t' =
//    t bits2<->3 swapped (flash16's PV layout). In this C-layout the permuted
//    bits live in `quad`: qp = ((quad&1)<<1)|(quad>>1).
// ---------------------------------------------------------------------------
__global__ __launch_bounds__(256) void qkv_mfma(
    const f16* __restrict__ Xt, const f16* __restrict__ Wqkv,
    const float* __restrict__ bq, const float* __restrict__ bkv,
    f16* __restrict__ Qh, f16* __restrict__ Kh, f16* __restrict__ Vh)
{
    __shared__ f16 As[128][40];
    __shared__ f16 Bs[128][40];
    const int tid = threadIdx.x;
    const int lane = tid & 63, w = tid >> 6;
    const int l15 = lane & 15, quad = lane >> 4;
    const int wy = w >> 1, wx = w & 1;
    const int mb0 = blockIdx.x * 128;   // token tile
    const int n0  = blockIdx.y * 128;   // channel tile (0..1535)

    f32x4 acc[4][4] = {};
    const int row = tid >> 2, c8 = (tid & 3) * 8;
    const f16* aptr = Xt + (size_t)mb0 * 512;
    const f16* bptr = Wqkv + (size_t)n0 * 512;

    uint4 ga0 = *(const uint4*)(aptr + (size_t)row * 512 + c8);
    uint4 ga1 = *(const uint4*)(aptr + (size_t)(row + 64) * 512 + c8);
    uint4 gb0 = *(const uint4*)(bptr + (size_t)row * 512 + c8);
    uint4 gb1 = *(const uint4*)(bptr + (size_t)(row + 64) * 512 + c8);

    for (int k0 = 0; k0 < 512; k0 += 32) {
        __syncthreads();
        *(uint4*)&As[row][c8] = ga0;
        *(uint4*)&As[row + 64][c8] = ga1;
        *(uint4*)&Bs[row][c8] = gb0;
        *(uint4*)&Bs[row + 64][c8] = gb1;
        if (k0 + 32 < 512) {
            ga0 = *(const uint4*)(aptr + (size_t)row * 512 + k0 + 32 + c8);
            ga1 = *(const uint4*)(aptr + (size_t)(row + 64) * 512 + k0 + 32 + c8);
            gb0 = *(const uint4*)(bptr + (size_t)row * 512 + k0 + 32 + c8);
            gb1 = *(const uint4*)(bptr + (size_t)(row + 64) * 512 + k0 + 32 + c8);
        }
        __syncthreads();
        f16x8 af[4], bf[4];
        #pragma unroll
        for (int i = 0; i < 4; ++i)
            af[i] = *(const f16x8*)&As[wy * 64 + i * 16 + l15][quad * 8];
        #pragma unroll
        for (int n = 0; n < 4; ++n)
            bf[n] = *(const f16x8*)&Bs[wx * 64 + n * 16 + l15][quad * 8];
        #pragma unroll
        for (int i = 0; i < 4; ++i)
            #pragma unroll
            for (int n = 0; n < 4; ++n)
                acc[i][n] = __builtin_amdgcn_mfma_f32_16x16x32_f16(af[i], bf[n], acc[i][n], 0, 0, 0);
    }

    // V-path: swap bits 2,3 of t (here t&15 = quad*4 + r -> swap quad's bits)
    const int qp = ((quad & 1) << 1) | (quad >> 1);

    #pragma unroll
    for (int nn = 0; nn < 4; ++nn) {
        const int o = n0 + wx * 64 + nn * 16 + l15;
        if (o < 1024) {
            const bool isQ = (o < 512);
            const float bias = isQ ? bq[o] : bkv[o - 512];
            const int h = (o & 511) >> 6, d = o & 63;
            f16* base = isQ ? Qh : Kh;
            #pragma unroll
            for (int i = 0; i < 4; ++i) {
                const int tr = mb0 + wy * 64 + i * 16 + quad * 4;
                #pragma unroll
                for (int r = 0; r < 4; ++r) {
                    const int tg = tr + r;
                    const int bh = (tg >> 12) * NH + h;
                    float v = acc[i][nn][r] + bias;
                    if (isQ) v *= QSC;
                    base[((size_t)bh * L_SEQ + (tg & 4095)) * DK + d] = (f16)v;
                }
            }
        } else {
            const int c = o - 1024;
            const float bias = bkv[512 + c];
            const int h = c >> 6, d = c & 63;
            #pragma unroll
            for (int i = 0; i < 4; ++i) {
                const int trp = mb0 + wy * 64 + i * 16 + qp * 4;  // permuted t base
                #pragma unroll
                for (int r = 0; r < 4; ++r) {
                    const int tq = trp + r;
                    const int bh = (tq >> 12) * NH + h;
                    const float v = acc[i][nn][r] + bias;
                    Vh[((size_t)bh * DK + d) * L_SEQ + (tq & 4095)] = (f16)v;
                }
            }
        }
    }
}

// ---------------------------------------------------------------------------
// Out-projection (verbatim r6 cproj_mfma, called with mode=1 only).
// m = channels (512), n = tokens (8192). A = Wh[o][c], B = Bsrc[t][c].
// mode 1: out-proj (fp32 out, [b][o][t]).
// ---------------------------------------------------------------------------
__global__ __launch_bounds__(256) void cproj_mfma(
    const f16* __restrict__ Bsrc, const f16* __restrict__ Wh,
    const float* __restrict__ bias, f16* __restrict__ outV,
    float* __restrict__ outP, int mode)
{
    __shared__ f16 As[128][40];
    __shared__ f16 Bs[128][40];
    const int tid = threadIdx.x;
    const int lane = tid & 63, w = tid >> 6;
    const int l15 = lane & 15, quad = lane >> 4;
    const int wy = w >> 1, wx = w & 1;
    const int n0  = blockIdx.x * 128;   // token tile
    const int mb0 = blockIdx.y * 128;   // channel tile

    f32x4 acc[4][4] = {};
    const int row = tid >> 2, c8 = (tid & 3) * 8;
    const f16* aptr = Wh + (size_t)mb0 * 512;
    const f16* bptr = Bsrc + (size_t)n0 * 512;

    uint4 ga0 = *(const uint4*)(aptr + (size_t)row * 512 + c8);
    uint4 ga1 = *(const uint4*)(aptr + (size_t)(row + 64) * 512 + c8);
    uint4 gb0 = *(const uint4*)(bptr + (size_t)row * 512 + c8);
    uint4 gb1 = *(const uint4*)(bptr + (size_t)(row + 64) * 512 + c8);

    for (int k0 = 0; k0 < 512; k0 += 32) {
        __syncthreads();
        *(uint4*)&As[row][c8] = ga0;
        *(uint4*)&As[row + 64][c8] = ga1;
        *(uint4*)&Bs[row][c8] = gb0;
        *(uint4*)&Bs[row + 64][c8] = gb1;
        if (k0 + 32 < 512) {
            ga0 = *(const uint4*)(aptr + (size_t)row * 512 + k0 + 32 + c8);
            ga1 = *(const uint4*)(aptr + (size_t)(row + 64) * 512 + k0 + 32 + c8);
            gb0 = *(const uint4*)(bptr + (size_t)row * 512 + k0 + 32 + c8);
            gb1 = *(const uint4*)(bptr + (size_t)(row + 64) * 512 + k0 + 32 + c8);
        }
        __syncthreads();
        f16x8 af[4], bf[4];
        #pragma unroll
        for (int i = 0; i < 4; ++i)
            af[i] = *(const f16x8*)&As[wy * 64 + i * 16 + l15][quad * 8];
        #pragma unroll
        for (int n = 0; n < 4; ++n)
            bf[n] = *(const f16x8*)&Bs[wx * 64 + n * 16 + l15][quad * 8];
        #pragma unroll
        for (int i = 0; i < 4; ++i)
            #pragma unroll
            for (int n = 0; n < 4; ++n)
                acc[i][n] = __builtin_amdgcn_mfma_f32_16x16x32_f16(af[i], bf[n], acc[i][n], 0, 0, 0);
    }

    // token-index low-4-bit permutation for V (swap bits 2 and 3); identity
    // on the t-index used by mode 1.
    const int l15p = (l15 & 3) | ((l15 & 4) << 1) | ((l15 & 8) >> 1);

    #pragma unroll
    for (int i = 0; i < 4; ++i) {
        #pragma unroll
        for (int r = 0; r < 4; ++r) {
            const int o = mb0 + wy * 64 + i * 16 + quad * 4 + r;   // channel
            const float bv = bias[o];
            #pragma unroll
            for (int nn = 0; nn < 4; ++nn) {
                const int tg = n0 + wx * 64 + nn * 16 + l15;
                const float v = acc[i][nn][r] + bv;
                if (mode == 0) {
                    const int tgp = (tg & ~15) | l15p;   // s-permuted store
                    const int bh = (tgp >> 12) * NH + (o >> 6);
                    outV[((size_t)bh * DK + (o & 63)) * L_SEQ + (tgp & 4095)] = (f16)v;
                } else {
                    outP[((size_t)(tg >> 12) * C_DIM + o) * L_SEQ + (tg & 4095)] = v;
                }
            }
        }
    }
}

// ---------------------------------------------------------------------------
// Flash attention v12 (unchanged, passing): PV-deferred pipeline,
// 32x32x16 MFMA, zero-shuffle P hand-off, b128-only LDS, 64-token waves.
// Partial O stored f16 [half*16+bh][d][t]; l f32 [half*16+bh][t].
// ---------------------------------------------------------------------------
__device__ __forceinline__ void gload_lds16(const char* g, char* l) {
    __builtin_amdgcn_global_load_lds(
        (const __attribute__((address_space(1))) void*)g,
        (__attribute__((address_space(3))) void*)l, 16, 0, 0);
}

union FR { u32 u[4]; f16x8 v; };

__device__ __forceinline__ void smax8(const f32x16& S, FR* fr, int base,
                                      float& rsv, h16x2 one2) {
    #pragma unroll
    for (int q = 0; q < 4; ++q) {
        const h16x2 a01 = __builtin_amdgcn_cvt_pkrtz(
            __builtin_amdgcn_exp2f(S[4 * q + 0]),
            __builtin_amdgcn_exp2f(S[4 * q + 1]));
        const h16x2 a23 = __builtin_amdgcn_cvt_pkrtz(
            __builtin_amdgcn_exp2f(S[4 * q + 2]),
            __builtin_amdgcn_exp2f(S[4 * q + 3]));
        rsv = __builtin_amdgcn_fdot2(a01, one2, rsv, false);
        rsv = __builtin_amdgcn_fdot2(a23, one2, rsv, false);
        union { h16x2 h; u32 u; } p0, p1; p0.h = a01; p1.h = a23;
        fr[base + (q >> 1)].u[(q & 1) * 2 + 0] = p0.u;
        fr[base + (q >> 1)].u[(q & 1) * 2 + 1] = p1.u;
    }
}

__global__ __launch_bounds__(256, 2) void flash16(
    const f16* __restrict__ Qh, const f16* __restrict__ Kh,
    const f16* __restrict__ Vh, f16* __restrict__ Opart,
    float* __restrict__ Lpart)
{
    __shared__ f16 KS[2][4096];        // [buf][s][d]  (cols bank-XOR swizzled)
    __shared__ f16 VS[3][4096];        // [buf][d][kk] (cols bank-XOR swizzled)
    const int tid = threadIdx.x;
    const int lane = tid & 63, w = tid >> 6;
    const int l31 = lane & 31, hl = lane >> 5;
    const int bh = blockIdx.x;          // XCD locality: bh % 8 picks the XCD
    const int t0 = blockIdx.y * 256;
    const int half = blockIdx.z;
    const int s_beg = half * 2048;
    const int wtb = t0 + w * 64;        // this wave's 64 tokens (2 x 32)
    const f16* Qg = Qh + (size_t)bh * L_SEQ * DK;
    const char* Kg = (const char*)(Kh + (size_t)bh * L_SEQ * DK);
    const char* Vg = (const char*)(Vh + (size_t)bh * DK * L_SEQ);

    // persistent Q B-fragments (already scaled by QSC): col=t, k=d
    f16x8 qf0[4], qf1[4];
    #pragma unroll
    for (int kst = 0; kst < 4; ++kst) {
        qf0[kst] = *(const f16x8*)(Qg + (size_t)(wtb + l31) * DK + kst * 16 + hl * 8);
        qf1[kst] = *(const f16x8*)(Qg + (size_t)(wtb + 32 + l31) * DK + kst * 16 + hl * 8);
    }

    // staging: 512 16B chunks per 8KB tile; thread covers chunks tid, tid+256.
    const int c0 = tid, c1 = tid + 256;
    const int kofs0 = (c0 >> 3) * 128  + (((c0 & 7) * 16) ^ (((c0 >> 3) & 7) << 4));
    const int kofs1 = (c1 >> 3) * 128  + (((c1 & 7) * 16) ^ (((c1 >> 3) & 7) << 4));
    const int vofs0 = (c0 >> 3) * 8192 + (((c0 & 7) * 16) ^ (((c0 >> 3) & 7) << 4));
    const int vofs1 = (c1 >> 3) * 8192 + (((c1 & 7) * 16) ^ (((c1 >> 3) & 7) << 4));
    const int lb0 = (w * 64) * 16, lb1 = (256 + w * 64) * 16;   // wave-uniform LDS bases

    #define STAGE_K(kb, s0v) do {                                    \
        const char* kg_ = Kg + (size_t)(s0v) * 128;                  \
        char* kl_ = (char*)&KS[kb][0];                               \
        gload_lds16(kg_ + kofs0, kl_ + lb0);                         \
        gload_lds16(kg_ + kofs1, kl_ + lb1);                         \
    } while (0)
    #define STAGE_V(vOfs, s0v) do {                                  \
        const char* vg_ = Vg + (size_t)(s0v) * 2;                    \
        char* vl_ = (char*)&VS[0][0] + (vOfs);                       \
        gload_lds16(vg_ + vofs0, vl_ + lb0);                         \
        gload_lds16(vg_ + vofs1, vl_ + lb1);                         \
    } while (0)

    f32x16 O00 = {}, O01 = {}, O10 = {}, O11 = {};   // [d-blk][t-blk]
    float rs0 = 0.f, rs1 = 0.f;
    h16x2 one2; one2[0] = (__fp16)1.f; one2[1] = (__fp16)1.f;
    FR frA0[4], frA1[4], frB0[4], frB1[4];

    STAGE_K(0, s_beg); STAGE_V(0, s_beg);
    __syncthreads();

    const int swz = (l31 & 7) << 4;
    const int rowA = l31 * 128, rowB = (32 + l31) * 128;

    // one iteration: stage(i+1), QK-A, softmax-A, QK-B + PV(i-1), softmax-B
    #define QKBODY(s0v, kbR, kbS, DOSTG, DOPV, stO, pvO, frC0, frC1, frP0, frP1) do { \
        if (DOSTG) { STAGE_K(kbS, (s0v) + 64); STAGE_V(stO, (s0v) + 64); }  \
        const char* Kb = (const char*)&KS[kbR][0];                          \
        f16x8 kf[4];                                                        \
        _Pragma("unroll")                                                   \
        for (int kst = 0; kst < 4; ++kst)                                   \
            kf[kst] = *(const f16x8*)(Kb + rowA + ((kst * 32 + hl * 16) ^ swz)); \
        {                                                                   \
            f32x16 Sa0 = {}, Sa1 = {};                                      \
            __builtin_amdgcn_s_setprio(1);                                  \
            _Pragma("unroll")                                               \
            for (int kst = 0; kst < 4; ++kst) {                             \
                Sa0 = __builtin_amdgcn_mfma_f32_32x32x16_f16(kf[kst], qf0[kst], Sa0, 0, 0, 0); \
                Sa1 = __builtin_amdgcn_mfma_f32_32x32x16_f16(kf[kst], qf1[kst], Sa1, 0, 0, 0); \
            }                                                               \
            __builtin_amdgcn_s_setprio(0);                                  \
            _Pragma("unroll")                                               \
            for (int kst = 0; kst < 4; ++kst)                               \
                kf[kst] = *(const f16x8*)(Kb + rowB + ((kst * 32 + hl * 16) ^ swz)); \
            smax8(Sa0, frC0, 0, rs0, one2);                                 \
            smax8(Sa1, frC1, 0, rs1, one2);                                 \
        }                                                                   \
        __builtin_amdgcn_sched_barrier(0);                                  \
        {                                                                   \
            f32x16 Sb0 = {}, Sb1 = {};                                      \
            __builtin_amdgcn_s_setprio(1);                                  \
            _Pragma("unroll")                                               \
            for (int kst = 0; kst < 4; ++kst) {                             \
                Sb0 = __builtin_amdgcn_mfma_f32_32x32x16_f16(kf[kst], qf0[kst], Sb0, 0, 0, 0); \
                Sb1 = __builtin_amdgcn_mfma_f32_32x32x16_f16(kf[kst], qf1[kst], Sb1, 0, 0, 0); \
            }                                                               \
            if (DOPV) {                                                     \
                const char* Vb = (const char*)&VS[0][0] + (pvO);            \
                _Pragma("unroll")                                           \
                for (int kst = 0; kst < 4; ++kst) {                         \
                    const int ca = (kst * 32 + hl * 16) ^ swz;              \
                    const f16x8 v0 = *(const f16x8*)(Vb + rowA + ca);       \
                    const f16x8 v1 = *(const f16x8*)(Vb + rowB + ca);       \
                    O00 = __builtin_amdgcn_mfma_f32_32x32x16_f16(v0, frP0[kst].v, O00, 0, 0, 0); \
                    O01 = __builtin_amdgcn_mfma_f32_32x32x16_f16(v0, frP1[kst].v, O01, 0, 0, 0); \
                    O10 = __builtin_amdgcn_mfma_f32_32x32x16_f16(v1, frP0[kst].v, O10, 0, 0, 0); \
                    O11 = __builtin_amdgcn_mfma_f32_32x32x16_f16(v1, frP1[kst].v, O11, 0, 0, 0); \
                }                                                           \
            }                                                               \
            __builtin_amdgcn_s_setprio(0);                                  \
            smax8(Sb0, frC0, 2, rs0, one2);                                 \
            smax8(Sb1, frC1, 2, rs1, one2);                                 \
        }                                                                   \
        __syncthreads();                                                    \
    } while (0)

    // it = 0: cur fr = A, no PV; stages tile1 -> KS[1], VS[1]
    QKBODY(s_beg, 0, 1, true, false, 8192, 0, frA0, frA1, frB0, frB1);

    int s0 = s_beg + 64;
    int stO = 16384, pvO = 0;   // it1: stage tile2 -> VS[2]; PV(0) -> VS[0]
    #pragma unroll 1
    for (int p = 0; p < 15; ++p) {
        // odd it: read KS[1], stage KS[0]; cur=frB, prev=frA
        QKBODY(s0, 1, 0, true, true, stO, pvO, frB0, frB1, frA0, frA1);
        s0 += 64; stO = (stO == 16384) ? 0 : stO + 8192; pvO = (pvO == 16384) ? 0 : pvO + 8192;
        // even it: read KS[0], stage KS[1]; cur=frA, prev=frB
        QKBODY(s0, 0, 1, true, true, stO, pvO, frA0, frA1, frB0, frB1);
        s0 += 64; stO = (stO == 16384) ? 0 : stO + 8192; pvO = (pvO == 16384) ? 0 : pvO + 8192;
    }
    // it = 31 (odd): last tile, no stage; PV(30) from VS[0]
    QKBODY(s0, 1, 0, false, true, 0, pvO, frB0, frB1, frA0, frA1);

    // epilogue: PV(31) -- tile31 lives in VS[31%3 = 1], fr in frB
    {
        const char* Vb = (const char*)&VS[0][0] + 8192;
        __builtin_amdgcn_s_setprio(1);
        #pragma unroll
        for (int kst = 0; kst < 4; ++kst) {
            const int ca = (kst * 32 + hl * 16) ^ swz;
            const f16x8 v0 = *(const f16x8*)(Vb + rowA + ca);
            const f16x8 v1 = *(const f16x8*)(Vb + rowB + ca);
            O00 = __builtin_amdgcn_mfma_f32_32x32x16_f16(v0, frB0[kst].v, O00, 0, 0, 0);
            O01 = __builtin_amdgcn_mfma_f32_32x32x16_f16(v0, frB1[kst].v, O01, 0, 0, 0);
            O10 = __builtin_amdgcn_mfma_f32_32x32x16_f16(v1, frB0[kst].v, O10, 0, 0, 0);
            O11 = __builtin_amdgcn_mfma_f32_32x32x16_f16(v1, frB1[kst].v, O11, 0, 0, 0);
        }
        __builtin_amdgcn_s_setprio(0);
    }
    #undef QKBODY
    #undef STAGE_K
    #undef STAGE_V

    // l partial: lane pair (l, l+32) covers all s for column t
    rs0 += __shfl_xor(rs0, 32, 64);
    rs1 += __shfl_xor(rs1, 32, 64);
    if (lane < 32) {
        float* Lp = Lpart + (size_t)(half * 16 + bh) * L_SEQ + wtb;
        Lp[l31] = rs0;
        Lp[32 + l31] = rs1;
    }

    // O partial: row d = db*32 + (r&3)+8*(r>>2)+4*hl, col t = wtb + tb*32 + l31
    f16* Op = Opart + (size_t)(half * 16 + bh) * DK * L_SEQ;
    #pragma unroll
    for (int r = 0; r < 16; ++r) {
        const int d = (r & 3) + 8 * (r >> 2) + 4 * hl;
        Op[(size_t)d * L_SEQ + wtb + l31] = (f16)O00[r];
        Op[(size_t)d * L_SEQ + wtb + 32 + l31] = (f16)O01[r];
        Op[(size_t)(32 + d) * L_SEQ + wtb + l31] = (f16)O10[r];
        Op[(size_t)(32 + d) * L_SEQ + wtb + 32 + l31] = (f16)O11[r];
    }
}

// ---------------------------------------------------------------------------
// combine (verbatim r6): O = (Olo + Ohi) / (llo + lhi), transpose [d][t] ->
// token-major f16 [b*4096+t][512] for the out-proj B operand.
// ---------------------------------------------------------------------------
__global__ __launch_bounds__(256) void combine(
    const f16* __restrict__ Opart, const float* __restrict__ Lpart,
    f16* __restrict__ Oh)
{
    __shared__ f16 Ts[64][72];
    __shared__ float Linv[64];
    const int tid = threadIdx.x;
    const int bh = blockIdx.y, b = bh >> 3, h = bh & 7;
    const int t0 = blockIdx.x * 64;
    if (tid < 64) {
        const float lo = Lpart[(size_t)bh * L_SEQ + t0 + tid];
        const float hi = Lpart[(size_t)(16 + bh) * L_SEQ + t0 + tid];
        Linv[tid] = 1.f / (lo + hi);
    }
    __syncthreads();
    const f16* Plo = Opart + (size_t)bh * DK * L_SEQ;
    const f16* Phi = Opart + (size_t)(16 + bh) * DK * L_SEQ;
    const int d = tid >> 4;
    const int tt = (tid & 15) * 4;
    #pragma unroll
    for (int p = 0; p < 4; ++p) {
        const int dd = d + p * 16;
        const size_t off = (size_t)dd * L_SEQ + t0 + tt;
        const f16x4 lo = *(const f16x4*)(Plo + off);
        const f16x4 hi = *(const f16x4*)(Phi + off);
        #pragma unroll
        for (int j = 0; j < 4; ++j)
            Ts[tt + j][dd] = (f16)(((float)lo[j] + (float)hi[j]) * Linv[tt + j]);
    }
    __syncthreads();
    const int tr = tid >> 2, ch = (tid & 3) * 16;
    f16* dst = Oh + ((size_t)(b * L_SEQ + t0 + tr)) * C_DIM + h * DK + ch;
    *(f16x8*)dst = *(const f16x8*)&Ts[tr][ch];
    *(f16x8*)(dst + 8) = *(const f16x8*)&Ts[tr][ch + 8];
}

// ---------------------------------------------------------------------------
extern "C" void kernel_launch(void* const* d_in, const int* in_sizes, int n_in,
                              void* d_out, int out_size, void* d_ws, size_t ws_size,
                              hipStream_t stream) {
    (void)in_sizes; (void)n_in; (void)out_size; (void)ws_size;
    const float* x   = (const float*)d_in[0];
    const float* Wq  = (const float*)d_in[1];
    const float* bq  = (const float*)d_in[2];
    const float* Wkv = (const float*)d_in[3];
    const float* bkv = (const float*)d_in[4];
    const float* Wp  = (const float*)d_in[5];
    const float* bp  = (const float*)d_in[6];
    float* out = (float*)d_out;

    f16* Xt    = (f16*)d_ws;           // [8192][512]
    f16* Wqkh  = Xt + 4194304;         // [1536][512] fused Wq|Wk|Wv
    f16* Wvh   = Wqkh + 524288;        //   (V rows, contiguous with Wqkh)
    f16* Wph   = Wvh + 262144;         // [512][512]
    f16* Qh    = Wph + 262144;         // [16][4096][64]
    f16* Kh    = Qh + 4194304;
    f16* Vh    = Kh + 4194304;         // [16*64][4096] (token idx bit2<->3 permuted)
    f16* Oh    = Vh + 4194304;         // [8192][512]
    f16* Opart = Oh + 4194304;         // [2*16][64][4096] f16
    float* Lpart = (float*)(Opart + 8388608);  // [2*16][4096] f32

    prep<<<dim3(128, 1, 3), 256, 0, stream>>>(x, Wq, Wkv, Wp, Xt, Wqkh, Wvh, Wph);
    qkv_mfma<<<dim3(64, 12), 256, 0, stream>>>(Xt, Wqkh, bq, bkv, Qh, Kh, Vh);
    flash16<<<dim3(16, 16, 2), 256, 0, stream>>>(Qh, Kh, Vh, Opart, Lpart);
    combine<<<dim3(64, 16), 256, 0, stream>>>(Opart, Lpart, Oh);
    cproj_mfma<<<dim3(64, 4), 256, 0, stream>>>(Oh, Wph, bp, nullptr, out, 1);
}

// Round 11
// 194.444 us; speedup vs baseline: 1.4577x; 1.0310x over previous
//
#include <hip/hip_runtime.h>
#include <math.h>

#define L_SEQ 4096
#define C_DIM 512
#define NH 8
#define DK 64
#define NB 2
#define QSC 0.18033688011112042f  /* (1/sqrt(64)) * log2(e) */

typedef _Float16 f16;
typedef _Float16 f16x8 __attribute__((ext_vector_type(8)));
typedef _Float16 f16x4 __attribute__((ext_vector_type(4)));
typedef __fp16 h16x2 __attribute__((ext_vector_type(2)));   // builtin ABI type
typedef float f32x4 __attribute__((ext_vector_type(4)));
typedef float f32x16 __attribute__((ext_vector_type(16)));
typedef unsigned int u32;

// ---------------------------------------------------------------------------
// prep: z=0,1 -> transpose-cast X[b] [512][4096] fp32 -> Xt [b*4096+t][512] f16
//       z=2   -> plain-cast Wq, Wkv[0:512], Wkv[512:1024], Wp -> f16
// (Wq, Wk, Wv land contiguously as Wqkv [1536][512] for the fused projection.)
// ---------------------------------------------------------------------------
__global__ __launch_bounds__(256) void prep(
    const float* __restrict__ X, const float* __restrict__ Wq,
    const float* __restrict__ Wkv, const float* __restrict__ Wp,
    f16* __restrict__ Xt, f16* __restrict__ Wqkh,
    f16* __restrict__ Wvh, f16* __restrict__ Wph)
{
    const int tid = threadIdx.x;
    const int z = blockIdx.z;
    if (z < 2) {
        __shared__ f16 Ts[64][72];
        const float* src = X + (size_t)z * C_DIM * L_SEQ;
        f16* dst = Xt + (size_t)z * L_SEQ * C_DIM;
        for (int tile = blockIdx.x; tile < 512; tile += gridDim.x) {
            const int c0 = (tile & 7) * 64;
            const int t0 = (tile >> 3) * 64;
            __syncthreads();
            #pragma unroll
            for (int p = 0; p < 4; ++p) {
                const int c = (tid >> 4) + p * 16;
                const int t = (tid & 15) * 4;
                const float4 v = *(const float4*)(src + (size_t)(c0 + c) * L_SEQ + t0 + t);
                Ts[t + 0][c] = (f16)v.x; Ts[t + 1][c] = (f16)v.y;
                Ts[t + 2][c] = (f16)v.z; Ts[t + 3][c] = (f16)v.w;
            }
            __syncthreads();
            #pragma unroll
            for (int p = 0; p < 2; ++p) {
                const int t = (tid >> 3) + p * 32;
                const int ch = (tid & 7) * 8;
                *(f16x8*)(dst + (size_t)(t0 + t) * C_DIM + c0 + ch) =
                    *(const f16x8*)&Ts[t][ch];
            }
        }
    } else {
        const float* srcs[4] = {Wq, Wkv, Wkv + 262144, Wp};
        f16* dsts[4] = {Wqkh, Wqkh + 262144, Wvh, Wph};
        #pragma unroll
        for (int s = 0; s < 4; ++s) {
            const float* sp = srcs[s]; f16* dp = dsts[s];
            for (int i = blockIdx.x * 256 + tid; i < 65536; i += gridDim.x * 256) {
                const float4 v = *(const float4*)(sp + (size_t)i * 4);
                f16x4 h; h[0] = (f16)v.x; h[1] = (f16)v.y; h[2] = (f16)v.z; h[3] = (f16)v.w;
                *(f16x4*)(dp + (size_t)i * 4) = h;
            }
        }
    }
}

// ---------------------------------------------------------------------------
// Fused Q/K/V projection, fp16 MFMA. m = tokens (8192), n = channels (1536).
// A = Xt[t][c], B = Wqkv[o][c] (Wq,Wk,Wv contiguous). C row=t, col=o.
//  o <  512: Q (bias bq, xQSC) -> Qh token-major [bh][t][64]
//  o < 1024: K (bias bkv)      -> Kh token-major
//  o >=1024: V (bias bkv[512+c]) -> Vh channel-major [bh][d][t'] with t' =
//    t bits2<->3 swapped (flash16's PV layout). In this C-layout the permuted
//    bits live in `quad`: qp = ((quad&1)<<1)|(quad>>1).
// ---------------------------------------------------------------------------
__global__ __launch_bounds__(256) void qkv_mfma(
    const f16* __restrict__ Xt, const f16* __restrict__ Wqkv,
    const float* __restrict__ bq, const float* __restrict__ bkv,
    f16* __restrict__ Qh, f16* __restrict__ Kh, f16* __restrict__ Vh)
{
    __shared__ f16 As[128][40];
    __shared__ f16 Bs[128][40];
    const int tid = threadIdx.x;
    const int lane = tid & 63, w = tid >> 6;
    const int l15 = lane & 15, quad = lane >> 4;
    const int wy = w >> 1, wx = w & 1;
    const int mb0 = blockIdx.x * 128;   // token tile
    const int n0  = blockIdx.y * 128;   // channel tile (0..1535)

    f32x4 acc[4][4] = {};
    const int row = tid >> 2, c8 = (tid & 3) * 8;
    const f16* aptr = Xt + (size_t)mb0 * 512;
    const f16* bptr = Wqkv + (size_t)n0 * 512;

    uint4 ga0 = *(const uint4*)(aptr + (size_t)row * 512 + c8);
    uint4 ga1 = *(const uint4*)(aptr + (size_t)(row + 64) * 512 + c8);
    uint4 gb0 = *(const uint4*)(bptr + (size_t)row * 512 + c8);
    uint4 gb1 = *(const uint4*)(bptr + (size_t)(row + 64) * 512 + c8);

    for (int k0 = 0; k0 < 512; k0 += 32) {
        __syncthreads();
        *(uint4*)&As[row][c8] = ga0;
        *(uint4*)&As[row + 64][c8] = ga1;
        *(uint4*)&Bs[row][c8] = gb0;
        *(uint4*)&Bs[row + 64][c8] = gb1;
        if (k0 + 32 < 512) {
            ga0 = *(const uint4*)(aptr + (size_t)row * 512 + k0 + 32 + c8);
            ga1 = *(const uint4*)(aptr + (size_t)(row + 64) * 512 + k0 + 32 + c8);
            gb0 = *(const uint4*)(bptr + (size_t)row * 512 + k0 + 32 + c8);
            gb1 = *(const uint4*)(bptr + (size_t)(row + 64) * 512 + k0 + 32 + c8);
        }
        __syncthreads();
        f16x8 af[4], bf[4];
        #pragma unroll
        for (int i = 0; i < 4; ++i)
            af[i] = *(const f16x8*)&As[wy * 64 + i * 16 + l15][quad * 8];
        #pragma unroll
        for (int n = 0; n < 4; ++n)
            bf[n] = *(const f16x8*)&Bs[wx * 64 + n * 16 + l15][quad * 8];
        #pragma unroll
        for (int i = 0; i < 4; ++i)
            #pragma unroll
            for (int n = 0; n < 4; ++n)
                acc[i][n] = __builtin_amdgcn_mfma_f32_16x16x32_f16(af[i], bf[n], acc[i][n], 0, 0, 0);
    }

    // V-path: swap bits 2,3 of t (here t&15 = quad*4 + r -> swap quad's bits)
    const int qp = ((quad & 1) << 1) | (quad >> 1);

    #pragma unroll
    for (int nn = 0; nn < 4; ++nn) {
        const int o = n0 + wx * 64 + nn * 16 + l15;
        if (o < 1024) {
            const bool isQ = (o < 512);
            const float bias = isQ ? bq[o] : bkv[o - 512];
            const int h = (o & 511) >> 6, d = o & 63;
            f16* base = isQ ? Qh : Kh;
            #pragma unroll
            for (int i = 0; i < 4; ++i) {
                const int tr = mb0 + wy * 64 + i * 16 + quad * 4;
                #pragma unroll
                for (int r = 0; r < 4; ++r) {
                    const int tg = tr + r;
                    const int bh = (tg >> 12) * NH + h;
                    float v = acc[i][nn][r] + bias;
                    if (isQ) v *= QSC;
                    base[((size_t)bh * L_SEQ + (tg & 4095)) * DK + d] = (f16)v;
                }
            }
        } else {
            const int c = o - 1024;
            const float bias = bkv[512 + c];
            const int h = c >> 6, d = c & 63;
            #pragma unroll
            for (int i = 0; i < 4; ++i) {
                const int trp = mb0 + wy * 64 + i * 16 + qp * 4;  // permuted t base
                #pragma unroll
                for (int r = 0; r < 4; ++r) {
                    const int tq = trp + r;
                    const int bh = (tq >> 12) * NH + h;
                    const float v = acc[i][nn][r] + bias;
                    Vh[((size_t)bh * DK + d) * L_SEQ + (tq & 4095)] = (f16)v;
                }
            }
        }
    }
}

// ---------------------------------------------------------------------------
// Out-projection, 64-channel tiles. m = channels (512, 64/block), n = tokens
// (8192, 128/block) -> grid (64,8) = 512 blocks = 2 blocks/CU (the r6 cproj
// at (64,4) was 1 block/CU = 1 wave/SIMD: every barrier drain fully exposed).
// B-side (Oh token-major staging) verbatim r6; A-side halved to As[64][40],
// acc[2][4]. fp32 out [b][o][t].
// ---------------------------------------------------------------------------
__global__ __launch_bounds__(256) void oproj2(
    const f16* __restrict__ Bsrc, const f16* __restrict__ Wh,
    const float* __restrict__ bias, float* __restrict__ outP)
{
    __shared__ f16 As[64][40];
    __shared__ f16 Bs[128][40];
    const int tid = threadIdx.x;
    const int lane = tid & 63, w = tid >> 6;
    const int l15 = lane & 15, quad = lane >> 4;
    const int wy = w >> 1, wx = w & 1;
    const int n0  = blockIdx.x * 128;   // token tile
    const int mb0 = blockIdx.y * 64;    // channel tile

    f32x4 acc[2][4] = {};
    const int row = tid >> 2, c8 = (tid & 3) * 8;
    const f16* aptr = Wh + (size_t)mb0 * 512;
    const f16* bptr = Bsrc + (size_t)n0 * 512;

    uint4 ga0 = *(const uint4*)(aptr + (size_t)row * 512 + c8);
    uint4 gb0 = *(const uint4*)(bptr + (size_t)row * 512 + c8);
    uint4 gb1 = *(const uint4*)(bptr + (size_t)(row + 64) * 512 + c8);

    for (int k0 = 0; k0 < 512; k0 += 32) {
        __syncthreads();
        *(uint4*)&As[row][c8] = ga0;
        *(uint4*)&Bs[row][c8] = gb0;
        *(uint4*)&Bs[row + 64][c8] = gb1;
        if (k0 + 32 < 512) {
            ga0 = *(const uint4*)(aptr + (size_t)row * 512 + k0 + 32 + c8);
            gb0 = *(const uint4*)(bptr + (size_t)row * 512 + k0 + 32 + c8);
            gb1 = *(const uint4*)(bptr + (size_t)(row + 64) * 512 + k0 + 32 + c8);
        }
        __syncthreads();
        f16x8 af[2], bf[4];
        #pragma unroll
        for (int i = 0; i < 2; ++i)
            af[i] = *(const f16x8*)&As[wy * 32 + i * 16 + l15][quad * 8];
        #pragma unroll
        for (int n = 0; n < 4; ++n)
            bf[n] = *(const f16x8*)&Bs[wx * 64 + n * 16 + l15][quad * 8];
        #pragma unroll
        for (int i = 0; i < 2; ++i)
            #pragma unroll
            for (int n = 0; n < 4; ++n)
                acc[i][n] = __builtin_amdgcn_mfma_f32_16x16x32_f16(af[i], bf[n], acc[i][n], 0, 0, 0);
    }

    #pragma unroll
    for (int i = 0; i < 2; ++i) {
        #pragma unroll
        for (int r = 0; r < 4; ++r) {
            const int o = mb0 + wy * 32 + i * 16 + quad * 4 + r;   // channel
            const float bv = bias[o];
            #pragma unroll
            for (int nn = 0; nn < 4; ++nn) {
                const int tg = n0 + wx * 64 + nn * 16 + l15;
                outP[((size_t)(tg >> 12) * C_DIM + o) * L_SEQ + (tg & 4095)] =
                    acc[i][nn][r] + bv;
            }
        }
    }
}

// ---------------------------------------------------------------------------
// Flash attention v12 (unchanged, passing): PV-deferred pipeline,
// 32x32x16 MFMA, zero-shuffle P hand-off, b128-only LDS, 64-token waves.
// Partial O stored f16 [half*16+bh][d][t]; l f32 [half*16+bh][t].
// ---------------------------------------------------------------------------
__device__ __forceinline__ void gload_lds16(const char* g, char* l) {
    __builtin_amdgcn_global_load_lds(
        (const __attribute__((address_space(1))) void*)g,
        (__attribute__((address_space(3))) void*)l, 16, 0, 0);
}

union FR { u32 u[4]; f16x8 v; };

__device__ __forceinline__ void smax8(const f32x16& S, FR* fr, int base,
                                      float& rsv, h16x2 one2) {
    #pragma unroll
    for (int q = 0; q < 4; ++q) {
        const h16x2 a01 = __builtin_amdgcn_cvt_pkrtz(
            __builtin_amdgcn_exp2f(S[4 * q + 0]),
            __builtin_amdgcn_exp2f(S[4 * q + 1]));
        const h16x2 a23 = __builtin_amdgcn_cvt_pkrtz(
            __builtin_amdgcn_exp2f(S[4 * q + 2]),
            __builtin_amdgcn_exp2f(S[4 * q + 3]));
        rsv = __builtin_amdgcn_fdot2(a01, one2, rsv, false);
        rsv = __builtin_amdgcn_fdot2(a23, one2, rsv, false);
        union { h16x2 h; u32 u; } p0, p1; p0.h = a01; p1.h = a23;
        fr[base + (q >> 1)].u[(q & 1) * 2 + 0] = p0.u;
        fr[base + (q >> 1)].u[(q & 1) * 2 + 1] = p1.u;
    }
}

__global__ __launch_bounds__(256, 2) void flash16(
    const f16* __restrict__ Qh, const f16* __restrict__ Kh,
    const f16* __restrict__ Vh, f16* __restrict__ Opart,
    float* __restrict__ Lpart)
{
    __shared__ f16 KS[2][4096];        // [buf][s][d]  (cols bank-XOR swizzled)
    __shared__ f16 VS[3][4096];        // [buf][d][kk] (cols bank-XOR swizzled)
    const int tid = threadIdx.x;
    const int lane = tid & 63, w = tid >> 6;
    const int l31 = lane & 31, hl = lane >> 5;
    const int bh = blockIdx.x;          // XCD locality: bh % 8 picks the XCD
    const int t0 = blockIdx.y * 256;
    const int half = blockIdx.z;
    const int s_beg = half * 2048;
    const int wtb = t0 + w * 64;        // this wave's 64 tokens (2 x 32)
    const f16* Qg = Qh + (size_t)bh * L_SEQ * DK;
    const char* Kg = (const char*)(Kh + (size_t)bh * L_SEQ * DK);
    const char* Vg = (const char*)(Vh + (size_t)bh * DK * L_SEQ);

    // persistent Q B-fragments (already scaled by QSC): col=t, k=d
    f16x8 qf0[4], qf1[4];
    #pragma unroll
    for (int kst = 0; kst < 4; ++kst) {
        qf0[kst] = *(const f16x8*)(Qg + (size_t)(wtb + l31) * DK + kst * 16 + hl * 8);
        qf1[kst] = *(const f16x8*)(Qg + (size_t)(wtb + 32 + l31) * DK + kst * 16 + hl * 8);
    }

    // staging: 512 16B chunks per 8KB tile; thread covers chunks tid, tid+256.
    const int c0 = tid, c1 = tid + 256;
    const int kofs0 = (c0 >> 3) * 128  + (((c0 & 7) * 16) ^ (((c0 >> 3) & 7) << 4));
    const int kofs1 = (c1 >> 3) * 128  + (((c1 & 7) * 16) ^ (((c1 >> 3) & 7) << 4));
    const int vofs0 = (c0 >> 3) * 8192 + (((c0 & 7) * 16) ^ (((c0 >> 3) & 7) << 4));
    const int vofs1 = (c1 >> 3) * 8192 + (((c1 & 7) * 16) ^ (((c1 >> 3) & 7) << 4));
    const int lb0 = (w * 64) * 16, lb1 = (256 + w * 64) * 16;   // wave-uniform LDS bases

    #define STAGE_K(kb, s0v) do {                                    \
        const char* kg_ = Kg + (size_t)(s0v) * 128;                  \
        char* kl_ = (char*)&KS[kb][0];                               \
        gload_lds16(kg_ + kofs0, kl_ + lb0);                         \
        gload_lds16(kg_ + kofs1, kl_ + lb1);                         \
    } while (0)
    #define STAGE_V(vOfs, s0v) do {                                  \
        const char* vg_ = Vg + (size_t)(s0v) * 2;                    \
        char* vl_ = (char*)&VS[0][0] + (vOfs);                       \
        gload_lds16(vg_ + vofs0, vl_ + lb0);                         \
        gload_lds16(vg_ + vofs1, vl_ + lb1);                         \
    } while (0)

    f32x16 O00 = {}, O01 = {}, O10 = {}, O11 = {};   // [d-blk][t-blk]
    float rs0 = 0.f, rs1 = 0.f;
    h16x2 one2; one2[0] = (__fp16)1.f; one2[1] = (__fp16)1.f;
    FR frA0[4], frA1[4], frB0[4], frB1[4];

    STAGE_K(0, s_beg); STAGE_V(0, s_beg);
    __syncthreads();

    const int swz = (l31 & 7) << 4;
    const int rowA = l31 * 128, rowB = (32 + l31) * 128;

    // one iteration: stage(i+1), QK-A, softmax-A, QK-B + PV(i-1), softmax-B
    #define QKBODY(s0v, kbR, kbS, DOSTG, DOPV, stO, pvO, frC0, frC1, frP0, frP1) do { \
        if (DOSTG) { STAGE_K(kbS, (s0v) + 64); STAGE_V(stO, (s0v) + 64); }  \
        const char* Kb = (const char*)&KS[kbR][0];                          \
        f16x8 kf[4];                                                        \
        _Pragma("unroll")                                                   \
        for (int kst = 0; kst < 4; ++kst)                                   \
            kf[kst] = *(const f16x8*)(Kb + rowA + ((kst * 32 + hl * 16) ^ swz)); \
        {                                                                   \
            f32x16 Sa0 = {}, Sa1 = {};                                      \
            __builtin_amdgcn_s_setprio(1);                                  \
            _Pragma("unroll")                                               \
            for (int kst = 0; kst < 4; ++kst) {                             \
                Sa0 = __builtin_amdgcn_mfma_f32_32x32x16_f16(kf[kst], qf0[kst], Sa0, 0, 0, 0); \
                Sa1 = __builtin_amdgcn_mfma_f32_32x32x16_f16(kf[kst], qf1[kst], Sa1, 0, 0, 0); \
            }                                                               \
            __builtin_amdgcn_s_setprio(0);                                  \
            _Pragma("unroll")                                               \
            for (int kst = 0; kst < 4; ++kst)                               \
                kf[kst] = *(const f16x8*)(Kb + rowB + ((kst * 32 + hl * 16) ^ swz)); \
            smax8(Sa0, frC0, 0, rs0, one2);                                 \
            smax8(Sa1, frC1, 0, rs1, one2);                                 \
        }                                                                   \
        __builtin_amdgcn_sched_barrier(0);                                  \
        {                                                                   \
            f32x16 Sb0 = {}, Sb1 = {};                                      \
            __builtin_amdgcn_s_setprio(1);                                  \
            _Pragma("unroll")                                               \
            for (int kst = 0; kst < 4; ++kst) {                             \
                Sb0 = __builtin_amdgcn_mfma_f32_32x32x16_f16(kf[kst], qf0[kst], Sb0, 0, 0, 0); \
                Sb1 = __builtin_amdgcn_mfma_f32_32x32x16_f16(kf[kst], qf1[kst], Sb1, 0, 0, 0); \
            }                                                               \
            if (DOPV) {                                                     \
                const char* Vb = (const char*)&VS[0][0] + (pvO);            \
                _Pragma("unroll")                                           \
                for (int kst = 0; kst < 4; ++kst) {                         \
                    const int ca = (kst * 32 + hl * 16) ^ swz;              \
                    const f16x8 v0 = *(const f16x8*)(Vb + rowA + ca);       \
                    const f16x8 v1 = *(const f16x8*)(Vb + rowB + ca);       \
                    O00 = __builtin_amdgcn_mfma_f32_32x32x16_f16(v0, frP0[kst].v, O00, 0, 0, 0); \
                    O01 = __builtin_amdgcn_mfma_f32_32x32x16_f16(v0, frP1[kst].v, O01, 0, 0, 0); \
                    O10 = __builtin_amdgcn_mfma_f32_32x32x16_f16(v1, frP0[kst].v, O10, 0, 0, 0); \
                    O11 = __builtin_amdgcn_mfma_f32_32x32x16_f16(v1, frP1[kst].v, O11, 0, 0, 0); \
                }                                                           \
            }                                                               \
            __builtin_amdgcn_s_setprio(0);                                  \
            smax8(Sb0, frC0, 2, rs0, one2);                                 \
            smax8(Sb1, frC1, 2, rs1, one2);                                 \
        }                                                                   \
        __syncthreads();                                                    \
    } while (0)

    // it = 0: cur fr = A, no PV; stages tile1 -> KS[1], VS[1]
    QKBODY(s_beg, 0, 1, true, false, 8192, 0, frA0, frA1, frB0, frB1);

    int s0 = s_beg + 64;
    int stO = 16384, pvO = 0;   // it1: stage tile2 -> VS[2]; PV(0) -> VS[0]
    #pragma unroll 1
    for (int p = 0; p < 15; ++p) {
        // odd it: read KS[1], stage KS[0]; cur=frB, prev=frA
        QKBODY(s0, 1, 0, true, true, stO, pvO, frB0, frB1, frA0, frA1);
        s0 += 64; stO = (stO == 16384) ? 0 : stO + 8192; pvO = (pvO == 16384) ? 0 : pvO + 8192;
        // even it: read KS[0], stage KS[1]; cur=frA, prev=frB
        QKBODY(s0, 0, 1, true, true, stO, pvO, frA0, frA1, frB0, frB1);
        s0 += 64; stO = (stO == 16384) ? 0 : stO + 8192; pvO = (pvO == 16384) ? 0 : pvO + 8192;
    }
    // it = 31 (odd): last tile, no stage; PV(30) from VS[0]
    QKBODY(s0, 1, 0, false, true, 0, pvO, frB0, frB1, frA0, frA1);

    // epilogue: PV(31) -- tile31 lives in VS[31%3 = 1], fr in frB
    {
        const char* Vb = (const char*)&VS[0][0] + 8192;
        __builtin_amdgcn_s_setprio(1);
        #pragma unroll
        for (int kst = 0; kst < 4; ++kst) {
            const int ca = (kst * 32 + hl * 16) ^ swz;
            const f16x8 v0 = *(const f16x8*)(Vb + rowA + ca);
            const f16x8 v1 = *(const f16x8*)(Vb + rowB + ca);
            O00 = __builtin_amdgcn_mfma_f32_32x32x16_f16(v0, frB0[kst].v, O00, 0, 0, 0);
            O01 = __builtin_amdgcn_mfma_f32_32x32x16_f16(v0, frB1[kst].v, O01, 0, 0, 0);
            O10 = __builtin_amdgcn_mfma_f32_32x32x16_f16(v1, frB0[kst].v, O10, 0, 0, 0);
            O11 = __builtin_amdgcn_mfma_f32_32x32x16_f16(v1, frB1[kst].v, O11, 0, 0, 0);
        }
        __builtin_amdgcn_s_setprio(0);
    }
    #undef QKBODY
    #undef STAGE_K
    #undef STAGE_V

    // l partial: lane pair (l, l+32) covers all s for column t
    rs0 += __shfl_xor(rs0, 32, 64);
    rs1 += __shfl_xor(rs1, 32, 64);
    if (lane < 32) {
        float* Lp = Lpart + (size_t)(half * 16 + bh) * L_SEQ + wtb;
        Lp[l31] = rs0;
        Lp[32 + l31] = rs1;
    }

    // O partial: row d = db*32 + (r&3)+8*(r>>2)+4*hl, col t = wtb + tb*32 + l31
    f16* Op = Opart + (size_t)(half * 16 + bh) * DK * L_SEQ;
    #pragma unroll
    for (int r = 0; r < 16; ++r) {
        const int d = (r & 3) + 8 * (r >> 2) + 4 * hl;
        Op[(size_t)d * L_SEQ + wtb + l31] = (f16)O00[r];
        Op[(size_t)d * L_SEQ + wtb + 32 + l31] = (f16)O01[r];
        Op[(size_t)(32 + d) * L_SEQ + wtb + l31] = (f16)O10[r];
        Op[(size_t)(32 + d) * L_SEQ + wtb + 32 + l31] = (f16)O11[r];
    }
}

// ---------------------------------------------------------------------------
// combine (verbatim r6): O = (Olo + Ohi) / (llo + lhi), transpose [d][t] ->
// token-major f16 [b*4096+t][512] for the out-proj B operand.
// ---------------------------------------------------------------------------
__global__ __launch_bounds__(256) void combine(
    const f16* __restrict__ Opart, const float* __restrict__ Lpart,
    f16* __restrict__ Oh)
{
    __shared__ f16 Ts[64][72];
    __shared__ float Linv[64];
    const int tid = threadIdx.x;
    const int bh = blockIdx.y, b = bh >> 3, h = bh & 7;
    const int t0 = blockIdx.x * 64;
    if (tid < 64) {
        const float lo = Lpart[(size_t)bh * L_SEQ + t0 + tid];
        const float hi = Lpart[(size_t)(16 + bh) * L_SEQ + t0 + tid];
        Linv[tid] = 1.f / (lo + hi);
    }
    __syncthreads();
    const f16* Plo = Opart + (size_t)bh * DK * L_SEQ;
    const f16* Phi = Opart + (size_t)(16 + bh) * DK * L_SEQ;
    const int d = tid >> 4;
    const int tt = (tid & 15) * 4;
    #pragma unroll
    for (int p = 0; p < 4; ++p) {
        const int dd = d + p * 16;
        const size_t off = (size_t)dd * L_SEQ + t0 + tt;
        const f16x4 lo = *(const f16x4*)(Plo + off);
        const f16x4 hi = *(const f16x4*)(Phi + off);
        #pragma unroll
        for (int j = 0; j < 4; ++j)
            Ts[tt + j][dd] = (f16)(((float)lo[j] + (float)hi[j]) * Linv[tt + j]);
    }
    __syncthreads();
    const int tr = tid >> 2, ch = (tid & 3) * 16;
    f16* dst = Oh + ((size_t)(b * L_SEQ + t0 + tr)) * C_DIM + h * DK + ch;
    *(f16x8*)dst = *(const f16x8*)&Ts[tr][ch];
    *(f16x8*)(dst + 8) = *(const f16x8*)&Ts[tr][ch + 8];
}

// ---------------------------------------------------------------------------
extern "C" void kernel_launch(void* const* d_in, const int* in_sizes, int n_in,
                              void* d_out, int out_size, void* d_ws, size_t ws_size,
                              hipStream_t stream) {
    (void)in_sizes; (void)n_in; (void)out_size; (void)ws_size;
    const float* x   = (const float*)d_in[0];
    const float* Wq  = (const float*)d_in[1];
    const float* bq  = (const float*)d_in[2];
    const float* Wkv = (const float*)d_in[3];
    const float* bkv = (const float*)d_in[4];
    const float* Wp  = (const float*)d_in[5];
    const float* bp  = (const float*)d_in[6];
    float* out = (float*)d_out;

    f16* Xt    = (f16*)d_ws;           // [8192][512]
    f16* Wqkh  = Xt + 4194304;         // [1536][512] fused Wq|Wk|Wv
    f16* Wvh   = Wqkh + 524288;        //   (V rows, contiguous with Wqkh)
    f16* Wph   = Wvh + 262144;         // [512][512]
    f16* Qh    = Wph + 262144;         // [16][4096][64]
    f16* Kh    = Qh + 4194304;
    f16* Vh    = Kh + 4194304;         // [16*64][4096] (token idx bit2<->3 permuted)
    f16* Oh    = Vh + 4194304;         // [8192][512]
    f16* Opart = Oh + 4194304;         // [2*16][64][4096] f16
    float* Lpart = (float*)(Opart + 8388608);  // [2*16][4096] f32

    prep<<<dim3(128, 1, 3), 256, 0, stream>>>(x, Wq, Wkv, Wp, Xt, Wqkh, Wvh, Wph);
    qkv_mfma<<<dim3(64, 12), 256, 0, stream>>>(Xt, Wqkh, bq, bkv, Qh, Kh, Vh);
    flash16<<<dim3(16, 16, 2), 256, 0, stream>>>(Qh, Kh, Vh, Opart, Lpart);
    combine<<<dim3(64, 16), 256, 0, stream>>>(Opart, Lpart, Oh);
    oproj2<<<dim3(64, 8), 256, 0, stream>>>(Oh, Wph, bp, out);
}

// Round 12
// 193.982 us; speedup vs baseline: 1.4612x; 1.0024x over previous
//
#include <hip/hip_runtime.h>
#include <math.h>

#define L_SEQ 4096
#define C_DIM 512
#define NH 8
#define DK 64
#define NB 2
#define QSC 0.18033688011112042f  /* (1/sqrt(64)) * log2(e) */

typedef _Float16 f16;
typedef _Float16 f16x8 __attribute__((ext_vector_type(8)));
typedef _Float16 f16x4 __attribute__((ext_vector_type(4)));
typedef __fp16 h16x2 __attribute__((ext_vector_type(2)));   // builtin ABI type
typedef float f32x4 __attribute__((ext_vector_type(4)));
typedef float f32x16 __attribute__((ext_vector_type(16)));
typedef unsigned int u32;

// ---------------------------------------------------------------------------
// prep: z=0,1 -> transpose-cast X[b] [512][4096] fp32 -> Xt [b*4096+t][512] f16
//       z=2   -> plain-cast Wq, Wkv[0:512], Wkv[512:1024], Wp -> f16
// (Wq, Wk, Wv land contiguously as Wqkv [1536][512] for the fused projection.)
// ---------------------------------------------------------------------------
__global__ __launch_bounds__(256) void prep(
    const float* __restrict__ X, const float* __restrict__ Wq,
    const float* __restrict__ Wkv, const float* __restrict__ Wp,
    f16* __restrict__ Xt, f16* __restrict__ Wqkh,
    f16* __restrict__ Wvh, f16* __restrict__ Wph)
{
    const int tid = threadIdx.x;
    const int z = blockIdx.z;
    if (z < 2) {
        __shared__ f16 Ts[64][72];
        const float* src = X + (size_t)z * C_DIM * L_SEQ;
        f16* dst = Xt + (size_t)z * L_SEQ * C_DIM;
        for (int tile = blockIdx.x; tile < 512; tile += gridDim.x) {
            const int c0 = (tile & 7) * 64;
            const int t0 = (tile >> 3) * 64;
            __syncthreads();
            #pragma unroll
            for (int p = 0; p < 4; ++p) {
                const int c = (tid >> 4) + p * 16;
                const int t = (tid & 15) * 4;
                const float4 v = *(const float4*)(src + (size_t)(c0 + c) * L_SEQ + t0 + t);
                Ts[t + 0][c] = (f16)v.x; Ts[t + 1][c] = (f16)v.y;
                Ts[t + 2][c] = (f16)v.z; Ts[t + 3][c] = (f16)v.w;
            }
            __syncthreads();
            #pragma unroll
            for (int p = 0; p < 2; ++p) {
                const int t = (tid >> 3) + p * 32;
                const int ch = (tid & 7) * 8;
                *(f16x8*)(dst + (size_t)(t0 + t) * C_DIM + c0 + ch) =
                    *(const f16x8*)&Ts[t][ch];
            }
        }
    } else {
        const float* srcs[4] = {Wq, Wkv, Wkv + 262144, Wp};
        f16* dsts[4] = {Wqkh, Wqkh + 262144, Wvh, Wph};
        #pragma unroll
        for (int s = 0; s < 4; ++s) {
            const float* sp = srcs[s]; f16* dp = dsts[s];
            for (int i = blockIdx.x * 256 + tid; i < 65536; i += gridDim.x * 256) {
                const float4 v = *(const float4*)(sp + (size_t)i * 4);
                f16x4 h; h[0] = (f16)v.x; h[1] = (f16)v.y; h[2] = (f16)v.z; h[3] = (f16)v.w;
                *(f16x4*)(dp + (size_t)i * 4) = h;
            }
        }
    }
}

// ---------------------------------------------------------------------------
// Fused Q/K/V projection, fp16 MFMA. m = tokens (8192), n = channels (1536).
// A = Xt[t][c], B = Wqkv[o][c] (Wq,Wk,Wv contiguous). C row=t, col=o.
//  o <  512: Q (bias bq, xQSC) -> Qh token-major [bh][t][64]
//  o < 1024: K (bias bkv)      -> Kh token-major
//  o >=1024: V (bias bkv[512+c]) -> Vh channel-major [bh][d][t'] with t' =
//    t bits2<->3 swapped (flash16's PV layout). In this C-layout the permuted
//    bits live in `quad`: qp = ((quad&1)<<1)|(quad>>1).
// ---------------------------------------------------------------------------
__global__ __launch_bounds__(256) void qkv_mfma(
    const f16* __restrict__ Xt, const f16* __restrict__ Wqkv,
    const float* __restrict__ bq, const float* __restrict__ bkv,
    f16* __restrict__ Qh, f16* __restrict__ Kh, f16* __restrict__ Vh)
{
    __shared__ f16 As[128][40];
    __shared__ f16 Bs[128][40];
    const int tid = threadIdx.x;
    const int lane = tid & 63, w = tid >> 6;
    const int l15 = lane & 15, quad = lane >> 4;
    const int wy = w >> 1, wx = w & 1;
    const int mb0 = blockIdx.x * 128;   // token tile
    const int n0  = blockIdx.y * 128;   // channel tile (0..1535)

    f32x4 acc[4][4] = {};
    const int row = tid >> 2, c8 = (tid & 3) * 8;
    const f16* aptr = Xt + (size_t)mb0 * 512;
    const f16* bptr = Wqkv + (size_t)n0 * 512;

    uint4 ga0 = *(const uint4*)(aptr + (size_t)row * 512 + c8);
    uint4 ga1 = *(const uint4*)(aptr + (size_t)(row + 64) * 512 + c8);
    uint4 gb0 = *(const uint4*)(bptr + (size_t)row * 512 + c8);
    uint4 gb1 = *(const uint4*)(bptr + (size_t)(row + 64) * 512 + c8);

    for (int k0 = 0; k0 < 512; k0 += 32) {
        __syncthreads();
        *(uint4*)&As[row][c8] = ga0;
        *(uint4*)&As[row + 64][c8] = ga1;
        *(uint4*)&Bs[row][c8] = gb0;
        *(uint4*)&Bs[row + 64][c8] = gb1;
        if (k0 + 32 < 512) {
            ga0 = *(const uint4*)(aptr + (size_t)row * 512 + k0 + 32 + c8);
            ga1 = *(const uint4*)(aptr + (size_t)(row + 64) * 512 + k0 + 32 + c8);
            gb0 = *(const uint4*)(bptr + (size_t)row * 512 + k0 + 32 + c8);
            gb1 = *(const uint4*)(bptr + (size_t)(row + 64) * 512 + k0 + 32 + c8);
        }
        __syncthreads();
        f16x8 af[4], bf[4];
        #pragma unroll
        for (int i = 0; i < 4; ++i)
            af[i] = *(const f16x8*)&As[wy * 64 + i * 16 + l15][quad * 8];
        #pragma unroll
        for (int n = 0; n < 4; ++n)
            bf[n] = *(const f16x8*)&Bs[wx * 64 + n * 16 + l15][quad * 8];
        #pragma unroll
        for (int i = 0; i < 4; ++i)
            #pragma unroll
            for (int n = 0; n < 4; ++n)
                acc[i][n] = __builtin_amdgcn_mfma_f32_16x16x32_f16(af[i], bf[n], acc[i][n], 0, 0, 0);
    }

    // V-path: swap bits 2,3 of t (here t&15 = quad*4 + r -> swap quad's bits)
    const int qp = ((quad & 1) << 1) | (quad >> 1);

    #pragma unroll
    for (int nn = 0; nn < 4; ++nn) {
        const int o = n0 + wx * 64 + nn * 16 + l15;
        if (o < 1024) {
            const bool isQ = (o < 512);
            const float bias = isQ ? bq[o] : bkv[o - 512];
            const int h = (o & 511) >> 6, d = o & 63;
            f16* base = isQ ? Qh : Kh;
            #pragma unroll
            for (int i = 0; i < 4; ++i) {
                const int tr = mb0 + wy * 64 + i * 16 + quad * 4;
                #pragma unroll
                for (int r = 0; r < 4; ++r) {
                    const int tg = tr + r;
                    const int bh = (tg >> 12) * NH + h;
                    float v = acc[i][nn][r] + bias;
                    if (isQ) v *= QSC;
                    base[((size_t)bh * L_SEQ + (tg & 4095)) * DK + d] = (f16)v;
                }
            }
        } else {
            const int c = o - 1024;
            const float bias = bkv[512 + c];
            const int h = c >> 6, d = c & 63;
            #pragma unroll
            for (int i = 0; i < 4; ++i) {
                const int trp = mb0 + wy * 64 + i * 16 + qp * 4;  // permuted t base
                #pragma unroll
                for (int r = 0; r < 4; ++r) {
                    const int tq = trp + r;
                    const int bh = (tq >> 12) * NH + h;
                    const float v = acc[i][nn][r] + bias;
                    Vh[((size_t)bh * DK + d) * L_SEQ + (tq & 4095)] = (f16)v;
                }
            }
        }
    }
}

// ---------------------------------------------------------------------------
// Out-projection (verbatim r11): 64-channel tiles, grid (64,8) = 2 blocks/CU.
// ---------------------------------------------------------------------------
__global__ __launch_bounds__(256) void oproj2(
    const f16* __restrict__ Bsrc, const f16* __restrict__ Wh,
    const float* __restrict__ bias, float* __restrict__ outP)
{
    __shared__ f16 As[64][40];
    __shared__ f16 Bs[128][40];
    const int tid = threadIdx.x;
    const int lane = tid & 63, w = tid >> 6;
    const int l15 = lane & 15, quad = lane >> 4;
    const int wy = w >> 1, wx = w & 1;
    const int n0  = blockIdx.x * 128;   // token tile
    const int mb0 = blockIdx.y * 64;    // channel tile

    f32x4 acc[2][4] = {};
    const int row = tid >> 2, c8 = (tid & 3) * 8;
    const f16* aptr = Wh + (size_t)mb0 * 512;
    const f16* bptr = Bsrc + (size_t)n0 * 512;

    uint4 ga0 = *(const uint4*)(aptr + (size_t)row * 512 + c8);
    uint4 gb0 = *(const uint4*)(bptr + (size_t)row * 512 + c8);
    uint4 gb1 = *(const uint4*)(bptr + (size_t)(row + 64) * 512 + c8);

    for (int k0 = 0; k0 < 512; k0 += 32) {
        __syncthreads();
        *(uint4*)&As[row][c8] = ga0;
        *(uint4*)&Bs[row][c8] = gb0;
        *(uint4*)&Bs[row + 64][c8] = gb1;
        if (k0 + 32 < 512) {
            ga0 = *(const uint4*)(aptr + (size_t)row * 512 + k0 + 32 + c8);
            gb0 = *(const uint4*)(bptr + (size_t)row * 512 + k0 + 32 + c8);
            gb1 = *(const uint4*)(bptr + (size_t)(row + 64) * 512 + k0 + 32 + c8);
        }
        __syncthreads();
        f16x8 af[2], bf[4];
        #pragma unroll
        for (int i = 0; i < 2; ++i)
            af[i] = *(const f16x8*)&As[wy * 32 + i * 16 + l15][quad * 8];
        #pragma unroll
        for (int n = 0; n < 4; ++n)
            bf[n] = *(const f16x8*)&Bs[wx * 64 + n * 16 + l15][quad * 8];
        #pragma unroll
        for (int i = 0; i < 2; ++i)
            #pragma unroll
            for (int n = 0; n < 4; ++n)
                acc[i][n] = __builtin_amdgcn_mfma_f32_16x16x32_f16(af[i], bf[n], acc[i][n], 0, 0, 0);
    }

    #pragma unroll
    for (int i = 0; i < 2; ++i) {
        #pragma unroll
        for (int r = 0; r < 4; ++r) {
            const int o = mb0 + wy * 32 + i * 16 + quad * 4 + r;   // channel
            const float bv = bias[o];
            #pragma unroll
            for (int nn = 0; nn < 4; ++nn) {
                const int tg = n0 + wx * 64 + nn * 16 + l15;
                outP[((size_t)(tg >> 12) * C_DIM + o) * L_SEQ + (tg & 4095)] =
                    acc[i][nn][r] + bv;
            }
        }
    }
}

// ---------------------------------------------------------------------------
// Flash attention v13: full-s per block (no split), in-kernel normalization,
// direct token-major Oh output -- the combine kernel is eliminated.
//  * Grid 16 bh x 32 t-tiles of 128; waves own 32 tokens; 64 s-iterations.
//  * v12's PV-deferred pipeline retained: QK(i) then PV(i-1) (fr in regs);
//    K double-buffered, V triple-buffered; 32x32x16 MFMA; zero-shuffle P
//    hand-off (Vh globally pre-permuted); b128-only XOR-swizzled LDS reads.
//  * After the loop rs = FULL softmax denominator (lane pair hl=0/1 via
//    shfl_xor 32) -> O *= 1/rs -> write Oh[b*4096+t][h*64+d] as f16x4 runs
//    (lane pairs fill contiguous 16B per row; 8 stores = full 128B slice).
// ---------------------------------------------------------------------------
__device__ __forceinline__ void gload_lds16(const char* g, char* l) {
    __builtin_amdgcn_global_load_lds(
        (const __attribute__((address_space(1))) void*)g,
        (__attribute__((address_space(3))) void*)l, 16, 0, 0);
}

union FR { u32 u[4]; f16x8 v; };

__device__ __forceinline__ void smax8(const f32x16& S, FR* fr, int base,
                                      float& rsv, h16x2 one2) {
    #pragma unroll
    for (int q = 0; q < 4; ++q) {
        const h16x2 a01 = __builtin_amdgcn_cvt_pkrtz(
            __builtin_amdgcn_exp2f(S[4 * q + 0]),
            __builtin_amdgcn_exp2f(S[4 * q + 1]));
        const h16x2 a23 = __builtin_amdgcn_cvt_pkrtz(
            __builtin_amdgcn_exp2f(S[4 * q + 2]),
            __builtin_amdgcn_exp2f(S[4 * q + 3]));
        rsv = __builtin_amdgcn_fdot2(a01, one2, rsv, false);
        rsv = __builtin_amdgcn_fdot2(a23, one2, rsv, false);
        union { h16x2 h; u32 u; } p0, p1; p0.h = a01; p1.h = a23;
        fr[base + (q >> 1)].u[(q & 1) * 2 + 0] = p0.u;
        fr[base + (q >> 1)].u[(q & 1) * 2 + 1] = p1.u;
    }
}

__global__ __launch_bounds__(256, 2) void flash16(
    const f16* __restrict__ Qh, const f16* __restrict__ Kh,
    const f16* __restrict__ Vh, f16* __restrict__ Oh)
{
    __shared__ f16 KS[2][4096];        // [buf][s][d]  (cols bank-XOR swizzled)
    __shared__ f16 VS[3][4096];        // [buf][d][kk] (cols bank-XOR swizzled)
    const int tid = threadIdx.x;
    const int lane = tid & 63, w = tid >> 6;
    const int l31 = lane & 31, hl = lane >> 5;
    const int bh = blockIdx.x;          // XCD locality: bh % 8 picks the XCD
    const int t0 = blockIdx.y * 128;
    const int wtb = t0 + w * 32;        // this wave's 32 tokens
    const f16* Qg = Qh + (size_t)bh * L_SEQ * DK;
    const char* Kg = (const char*)(Kh + (size_t)bh * L_SEQ * DK);
    const char* Vg = (const char*)(Vh + (size_t)bh * DK * L_SEQ);

    // persistent Q B-fragments (already scaled by QSC): col=t=l31, k=d
    f16x8 qf[4];
    #pragma unroll
    for (int kst = 0; kst < 4; ++kst)
        qf[kst] = *(const f16x8*)(Qg + (size_t)(wtb + l31) * DK + kst * 16 + hl * 8);

    // staging: 512 16B chunks per 8KB tile; thread covers chunks tid, tid+256.
    const int c0 = tid, c1 = tid + 256;
    const int kofs0 = (c0 >> 3) * 128  + (((c0 & 7) * 16) ^ (((c0 >> 3) & 7) << 4));
    const int kofs1 = (c1 >> 3) * 128  + (((c1 & 7) * 16) ^ (((c1 >> 3) & 7) << 4));
    const int vofs0 = (c0 >> 3) * 8192 + (((c0 & 7) * 16) ^ (((c0 >> 3) & 7) << 4));
    const int vofs1 = (c1 >> 3) * 8192 + (((c1 & 7) * 16) ^ (((c1 >> 3) & 7) << 4));
    const int lb0 = (w * 64) * 16, lb1 = (256 + w * 64) * 16;   // wave-uniform LDS bases

    #define STAGE_K(kb, s0v) do {                                    \
        const char* kg_ = Kg + (size_t)(s0v) * 128;                  \
        char* kl_ = (char*)&KS[kb][0];                               \
        gload_lds16(kg_ + kofs0, kl_ + lb0);                         \
        gload_lds16(kg_ + kofs1, kl_ + lb1);                         \
    } while (0)
    #define STAGE_V(vOfs, s0v) do {                                  \
        const char* vg_ = Vg + (size_t)(s0v) * 2;                    \
        char* vl_ = (char*)&VS[0][0] + (vOfs);                       \
        gload_lds16(vg_ + vofs0, vl_ + lb0);                         \
        gload_lds16(vg_ + vofs1, vl_ + lb1);                         \
    } while (0)

    f32x16 O0 = {}, O1 = {};            // [d-blk]
    float rs = 0.f;
    h16x2 one2; one2[0] = (__fp16)1.f; one2[1] = (__fp16)1.f;
    FR frA[4], frB[4];

    STAGE_K(0, 0); STAGE_V(0, 0);
    __syncthreads();

    const int swz = (l31 & 7) << 4;
    const int rowA = l31 * 128, rowB = (32 + l31) * 128;

    // one iteration: stage(i+1), QK-A, softmax-A, QK-B + PV(i-1), softmax-B
    #define QKBODY(s0v, kbR, kbS, DOSTG, DOPV, stO, pvO, frC, frP) do {     \
        if (DOSTG) { STAGE_K(kbS, (s0v) + 64); STAGE_V(stO, (s0v) + 64); }  \
        const char* Kb = (const char*)&KS[kbR][0];                          \
        f16x8 kf[4];                                                        \
        _Pragma("unroll")                                                   \
        for (int kst = 0; kst < 4; ++kst)                                   \
            kf[kst] = *(const f16x8*)(Kb + rowA + ((kst * 32 + hl * 16) ^ swz)); \
        {                                                                   \
            f32x16 Sa = {};                                                 \
            __builtin_amdgcn_s_setprio(1);                                  \
            _Pragma("unroll")                                               \
            for (int kst = 0; kst < 4; ++kst)                               \
                Sa = __builtin_amdgcn_mfma_f32_32x32x16_f16(kf[kst], qf[kst], Sa, 0, 0, 0); \
            __builtin_amdgcn_s_setprio(0);                                  \
            _Pragma("unroll")                                               \
            for (int kst = 0; kst < 4; ++kst)                               \
                kf[kst] = *(const f16x8*)(Kb + rowB + ((kst * 32 + hl * 16) ^ swz)); \
            smax8(Sa, frC, 0, rs, one2);                                    \
        }                                                                   \
        __builtin_amdgcn_sched_barrier(0);                                  \
        {                                                                   \
            f32x16 Sb = {};                                                 \
            __builtin_amdgcn_s_setprio(1);                                  \
            _Pragma("unroll")                                               \
            for (int kst = 0; kst < 4; ++kst)                               \
                Sb = __builtin_amdgcn_mfma_f32_32x32x16_f16(kf[kst], qf[kst], Sb, 0, 0, 0); \
            if (DOPV) {                                                     \
                const char* Vb = (const char*)&VS[0][0] + (pvO);            \
                _Pragma("unroll")                                           \
                for (int kst = 0; kst < 4; ++kst) {                         \
                    const int ca = (kst * 32 + hl * 16) ^ swz;              \
                    const f16x8 v0 = *(const f16x8*)(Vb + rowA + ca);       \
                    const f16x8 v1 = *(const f16x8*)(Vb + rowB + ca);       \
                    O0 = __builtin_amdgcn_mfma_f32_32x32x16_f16(v0, frP[kst].v, O0, 0, 0, 0); \
                    O1 = __builtin_amdgcn_mfma_f32_32x32x16_f16(v1, frP[kst].v, O1, 0, 0, 0); \
                }                                                           \
            }                                                               \
            __builtin_amdgcn_s_setprio(0);                                  \
            smax8(Sb, frC, 2, rs, one2);                                    \
        }                                                                   \
        __syncthreads();                                                    \
    } while (0)

    // it = 0: cur fr = A, no PV; stages tile1 -> KS[1], VS[1]
    QKBODY(0, 0, 1, true, false, 8192, 0, frA, frB);

    int s0 = 64;
    int stO = 16384, pvO = 0;   // it1: stage tile2 -> VS[2]; PV(0) -> VS[0]
    #pragma unroll 1
    for (int p = 0; p < 31; ++p) {
        // odd it: read KS[1], stage KS[0]; cur=frB, prev=frA
        QKBODY(s0, 1, 0, true, true, stO, pvO, frB, frA);
        s0 += 64; stO = (stO == 16384) ? 0 : stO + 8192; pvO = (pvO == 16384) ? 0 : pvO + 8192;
        // even it: read KS[0], stage KS[1]; cur=frA, prev=frB
        QKBODY(s0, 0, 1, true, true, stO, pvO, frA, frB);
        s0 += 64; stO = (stO == 16384) ? 0 : stO + 8192; pvO = (pvO == 16384) ? 0 : pvO + 8192;
    }
    // it = 63 (odd): last tile, no stage; PV(62) from VS[62%3=2] (pvO=16384)
    QKBODY(s0, 1, 0, false, true, 0, pvO, frB, frA);

    // epilogue: PV(63) -- tile63 lives in VS[63%3 = 0], fr in frB
    {
        const char* Vb = (const char*)&VS[0][0];
        __builtin_amdgcn_s_setprio(1);
        #pragma unroll
        for (int kst = 0; kst < 4; ++kst) {
            const int ca = (kst * 32 + hl * 16) ^ swz;
            const f16x8 v0 = *(const f16x8*)(Vb + rowA + ca);
            const f16x8 v1 = *(const f16x8*)(Vb + rowB + ca);
            O0 = __builtin_amdgcn_mfma_f32_32x32x16_f16(v0, frB[kst].v, O0, 0, 0, 0);
            O1 = __builtin_amdgcn_mfma_f32_32x32x16_f16(v1, frB[kst].v, O1, 0, 0, 0);
        }
        __builtin_amdgcn_s_setprio(0);
    }
    #undef QKBODY
    #undef STAGE_K
    #undef STAGE_V

    // full softmax denominator: lane pair (l, l+32) covers all s for column t
    rs += __shfl_xor(rs, 32, 64);
    const float rinv = 1.f / rs;

    // normalized O -> token-major Oh[b*4096+t][h*64+d]
    // lane (l31,hl): t = wtb+l31; d = 8*run + 4*hl + j (+32 for O1)
    const int b = bh >> 3, h = bh & 7;
    f16* OhP = Oh + ((size_t)(b * L_SEQ + wtb + l31)) * C_DIM + h * DK;
    #pragma unroll
    for (int run = 0; run < 4; ++run) {
        f16x4 v0, v1;
        #pragma unroll
        for (int j = 0; j < 4; ++j) {
            v0[j] = (f16)(O0[run * 4 + j] * rinv);
            v1[j] = (f16)(O1[run * 4 + j] * rinv);
        }
        *(f16x4*)(OhP + run * 8 + 4 * hl) = v0;
        *(f16x4*)(OhP + 32 + run * 8 + 4 * hl) = v1;
    }
}

// ---------------------------------------------------------------------------
extern "C" void kernel_launch(void* const* d_in, const int* in_sizes, int n_in,
                              void* d_out, int out_size, void* d_ws, size_t ws_size,
                              hipStream_t stream) {
    (void)in_sizes; (void)n_in; (void)out_size; (void)ws_size;
    const float* x   = (const float*)d_in[0];
    const float* Wq  = (const float*)d_in[1];
    const float* bq  = (const float*)d_in[2];
    const float* Wkv = (const float*)d_in[3];
    const float* bkv = (const float*)d_in[4];
    const float* Wp  = (const float*)d_in[5];
    const float* bp  = (const float*)d_in[6];
    float* out = (float*)d_out;

    f16* Xt    = (f16*)d_ws;           // [8192][512]
    f16* Wqkh  = Xt + 4194304;         // [1536][512] fused Wq|Wk|Wv
    f16* Wvh   = Wqkh + 524288;        //   (V rows, contiguous with Wqkh)
    f16* Wph   = Wvh + 262144;         // [512][512]
    f16* Qh    = Wph + 262144;         // [16][4096][64]
    f16* Kh    = Qh + 4194304;
    f16* Vh    = Kh + 4194304;         // [16*64][4096] (token idx bit2<->3 permuted)
    f16* Oh    = Vh + 4194304;         // [8192][512]

    prep<<<dim3(128, 1, 3), 256, 0, stream>>>(x, Wq, Wkv, Wp, Xt, Wqkh, Wvh, Wph);
    qkv_mfma<<<dim3(64, 12), 256, 0, stream>>>(Xt, Wqkh, bq, bkv, Qh, Kh, Vh);
    flash16<<<dim3(16, 32), 256, 0, stream>>>(Qh, Kh, Vh, Oh);
    oproj2<<<dim3(64, 8), 256, 0, stream>>>(Oh, Wph, bp, out);
}